// Round 10
// baseline (1442.321 us; speedup 1.0000x reference)
//
#include <hip/hip_runtime.h>
#include <hip/hip_bf16.h>
#include <hip/hip_cooperative_groups.h>
namespace cg = cooperative_groups;

// Dims
#define BATCH 16
#define SEQ 1024
#define NROWS (BATCH*SEQ)          // 16384 tokens
#define IN_DIM 768
#define DM 128
#define DIP 644
#define DI 256
#define CDIM 384
#define DST 64
#define NH 4
#define HD 64
#define CHUNK 64
#define NCHUNK (SEQ/CHUNK)         // 16

// bf16 weight area offsets (in shorts)
#define WB_FC1   0          // [128][768]
#define WB_IN    98304      // [2][644][128]
#define WB_OUT   263168     // [2][128][256]
#define WB_FC2   328704     // [128][128]
#define WB_TOTAL 345088

typedef __attribute__((ext_vector_type(8))) short short8;
typedef __attribute__((ext_vector_type(4))) float float4v;

// f32 -> bf16 (RNE) as raw short
__device__ __forceinline__ short f2b(float f) {
    unsigned u = __builtin_bit_cast(unsigned, f);
    u += 0x7fffu + ((u >> 16) & 1u);
    return (short)(u >> 16);
}
__device__ __forceinline__ float s2f(short s) {
    unsigned u = ((unsigned)(unsigned short)s) << 16;
    return __builtin_bit_cast(float, u);
}
__device__ __forceinline__ float silu(float a) { return a / (1.f + expf(-a)); }

// ---------------- weight prep: convert + transpose to bf16 ----------------
__global__ void prep_weights(const float* __restrict__ fc1_W, const float* __restrict__ in_W,
                             const float* __restrict__ out_W, const float* __restrict__ fc2_W1,
                             short* __restrict__ wb) {
    int idx = blockIdx.x * 256 + threadIdx.x;
    if (idx < 98304) {                       // fc1_Wt[n][k] <- fc1_W[k][n]
        int n = idx / 768, k = idx % 768;
        wb[WB_FC1 + idx] = f2b(fc1_W[k * 128 + n]);
        return;
    }
    idx -= 98304;
    if (idx < 2 * 82432) {                   // in_Wt[l][n][k] <- in_W[l][k][n]
        int l = idx / 82432, r = idx % 82432;
        int n = r / 128, k = r % 128;
        wb[WB_IN + idx] = f2b(in_W[(size_t)l * 82432 + k * 644 + n]);
        return;
    }
    idx -= 164864;
    if (idx < 2 * 32768) {                   // out_Wt[l][n][k] <- out_W[l][k][n]
        int l = idx / 32768, r = idx % 32768;
        int n = r / 256, k = r % 256;
        wb[WB_OUT + idx] = f2b(out_W[(size_t)l * 32768 + k * 128 + n]);
        return;
    }
    idx -= 65536;
    if (idx < 16384) {                       // fc2_W1t[n][k] <- fc2_W1[k][n]
        int n = idx / 128, k = idx % 128;
        wb[WB_FC2 + idx] = f2b(fc2_W1[k * 128 + n]);
    }
}

// ---------------- fc1 (MFMA, M=32, dbuf LDS, 1 barrier/K-tile) + PE + register-LN ----------------
__global__ __launch_bounds__(512) void fc1_mfma(const float* __restrict__ x,
                                                const short* __restrict__ wt,
                                                const float* __restrict__ bias,
                                                const float* __restrict__ lnw0,
                                                const float* __restrict__ lnb0,
                                                float* __restrict__ h,
                                                short* __restrict__ hnb) {
    __shared__ short As[2][32 * 72];
    __shared__ short Bt[2][128 * 72];
    __shared__ float ps1[32][4], ps2[32][4];
    int tid = threadIdx.x;
    int lane = tid & 63;
    int m = lane & 15;
    int quad = lane >> 4;
    int kq = quad * 8;
    int w = tid >> 6;              // 0..7
    int mrow = (w & 1) * 16;
    int ngrp = w >> 1;             // 0..3 -> cols ngrp*32 .. +31
    int ar = tid >> 4;             // 0..31
    int ac = (tid & 15) * 4;       // 0..60
    int row0 = blockIdx.x * 32;
    float4v acc[2];
    acc[0] = (float4v)0.f; acc[1] = (float4v)0.f;

#define FC1_STAGE(BI, KT) { \
        const float* src = x + (size_t)(row0 + ar) * IN_DIM + (KT) * 64 + ac; \
        float4 v = *(const float4*)src; \
        short4 pv; pv.x = f2b(v.x); pv.y = f2b(v.y); pv.z = f2b(v.z); pv.w = f2b(v.w); \
        *reinterpret_cast<short4*>(&As[BI][ar * 72 + ac]) = pv; \
        _Pragma("unroll") \
        for (int i = 0; i < 2; i++) { \
            int idx = tid + i * 512; \
            int n = idx >> 3, kk = (idx & 7) * 8; \
            *reinterpret_cast<short8*>(&Bt[BI][n * 72 + kk]) = \
                *reinterpret_cast<const short8*>(&wt[n * 768 + (KT) * 64 + kk]); \
        } }

    FC1_STAGE(0, 0)
    __syncthreads();
    int buf = 0;
    for (int kt = 0; kt < 12; kt++) {
        int nb = buf ^ 1;
        if (kt < 11) FC1_STAGE(nb, kt + 1)
        short8 a0 = *reinterpret_cast<const short8*>(&As[buf][(mrow + m) * 72 + kq]);
        short8 a1 = *reinterpret_cast<const short8*>(&As[buf][(mrow + m) * 72 + kq + 32]);
        #pragma unroll
        for (int nt = 0; nt < 2; nt++) {
            int bo = (ngrp * 32 + nt * 16 + m) * 72 + kq;
            short8 b0 = *reinterpret_cast<const short8*>(&Bt[buf][bo]);
            short8 b1 = *reinterpret_cast<const short8*>(&Bt[buf][bo + 32]);
            acc[nt] = __builtin_amdgcn_mfma_f32_16x16x32_bf16(a0, b0, acc[nt], 0, 0, 0);
            acc[nt] = __builtin_amdgcn_mfma_f32_16x16x32_bf16(a1, b1, acc[nt], 0, 0, 0);
        }
        __syncthreads();
        buf = nb;
    }
    float val[2][4];
    float s1r[4] = {0.f,0.f,0.f,0.f}, s2r[4] = {0.f,0.f,0.f,0.f};
    #pragma unroll
    for (int nt = 0; nt < 2; nt++) {
        int col = ngrp * 32 + nt * 16 + m;
        float bv = bias[col];
        float div = expf(-(float)(col & ~1) * 0.071955784f);
        #pragma unroll
        for (int r = 0; r < 4; r++) {
            int row = row0 + mrow + quad * 4 + r;
            int t = row & (SEQ - 1);
            float arg = (float)t * div;
            float pe = (col & 1) ? cosf(arg) : sinf(arg);
            float v = acc[nt][r] + bv + pe;
            val[nt][r] = v;
            s1r[r] += v; s2r[r] += v * v;
        }
    }
    #pragma unroll
    for (int o = 1; o < 16; o <<= 1) {
        #pragma unroll
        for (int r = 0; r < 4; r++) {
            s1r[r] += __shfl_xor(s1r[r], o);
            s2r[r] += __shfl_xor(s2r[r], o);
        }
    }
    if (m == 0) {
        #pragma unroll
        for (int r = 0; r < 4; r++) {
            ps1[mrow + quad * 4 + r][ngrp] = s1r[r];
            ps2[mrow + quad * 4 + r][ngrp] = s2r[r];
        }
    }
    __syncthreads();
    #pragma unroll
    for (int r = 0; r < 4; r++) {
        int rl = mrow + quad * 4 + r;
        float s1 = ps1[rl][0] + ps1[rl][1] + ps1[rl][2] + ps1[rl][3];
        float s2 = ps2[rl][0] + ps2[rl][1] + ps2[rl][2] + ps2[rl][3];
        float mu = s1 * (1.f / 128.f);
        float rs = rsqrtf(s2 * (1.f / 128.f) - mu * mu + 1e-5f);
        int row = row0 + rl;
        #pragma unroll
        for (int nt = 0; nt < 2; nt++) {
            int col = ngrp * 32 + nt * 16 + m;
            float v = val[nt][r];
            h[(size_t)row * DM + col] = v;
            hnb[(size_t)row * DM + col] = f2b((v - mu) * rs * lnw0[col] + lnb0[col]);
        }
    }
}

// ---------------- fallback: in_proj full-K single-barrier ----------------
__global__ __launch_bounds__(512) void inproj_mfma(const short* __restrict__ hnb,
                                                   const short* __restrict__ wb,
                                                   short* __restrict__ zb,
                                                   short* __restrict__ xbc,
                                                   int layer) {
    __shared__ short As[64 * 136];
    __shared__ short Bt[128 * 136];
    int tid = threadIdx.x;
    int lane = tid & 63;
    int m = lane & 15;
    int kq = (lane >> 4) * 8;
    int w = tid >> 6;
    int mrow = (w & 3) * 16;
    int ngrp = w >> 2;
    int row0 = blockIdx.x * 64;
    int ncol0 = blockIdx.y * 128;
    const short* wt = wb + WB_IN + (size_t)layer * 82432;
    {
        const short* src = hnb + (size_t)row0 * DM;
        #pragma unroll
        for (int i = 0; i < 2; i++) {
            int u = i * 512 + tid;
            *reinterpret_cast<short8*>(&As[(u >> 4) * 136 + (u & 15) * 8]) =
                *reinterpret_cast<const short8*>(&src[u * 8]);
        }
        #pragma unroll
        for (int i = 0; i < 4; i++) {
            int u = i * 512 + tid;
            int n = u >> 4, c8 = (u & 15) * 8;
            *reinterpret_cast<short8*>(&Bt[n * 136 + c8]) =
                *reinterpret_cast<const short8*>(&wt[(ncol0 + n) * 128 + c8]);
        }
    }
    __syncthreads();
    float4v acc[4];
    acc[0] = (float4v)0.f; acc[1] = (float4v)0.f; acc[2] = (float4v)0.f; acc[3] = (float4v)0.f;
    #pragma unroll
    for (int ks = 0; ks < 4; ks++) {
        short8 a = *reinterpret_cast<const short8*>(&As[(mrow + m) * 136 + ks * 32 + kq]);
        #pragma unroll
        for (int nt = 0; nt < 4; nt++) {
            short8 b = *reinterpret_cast<const short8*>(
                &Bt[(ngrp * 64 + nt * 16 + m) * 136 + ks * 32 + kq]);
            acc[nt] = __builtin_amdgcn_mfma_f32_16x16x32_bf16(a, b, acc[nt], 0, 0, 0);
        }
    }
    int colbase = ncol0 + ngrp * 64;
    if (ncol0 < DI) {
        #pragma unroll
        for (int nt = 0; nt < 4; nt++) {
            int col = colbase + nt * 16 + m;
            #pragma unroll
            for (int r = 0; r < 4; r++) {
                int row = row0 + mrow + (lane >> 4) * 4 + r;
                zb[(size_t)row * DI + col] = f2b(acc[nt][r]);
            }
        }
    } else {
        int xbase = colbase - DI;
        #pragma unroll
        for (int nt = 0; nt < 4; nt++) {
            int col = xbase + nt * 16 + m;
            #pragma unroll
            for (int r = 0; r < 4; r++) {
                int row = row0 + mrow + (lane >> 4) * 4 + r;
                xbc[(size_t)row * CDIM + col] = f2b(acc[nt][r]);
            }
        }
    }
}

// ---------------- fallback: causal conv(4) + SiLU + dt GEMV ----------------
__global__ void conv_kernel(const short* __restrict__ xbc,
                            const float* __restrict__ convw, const float* __restrict__ convb,
                            short* __restrict__ xcb,
                            const short* __restrict__ hnb, const short* __restrict__ wb,
                            const float* __restrict__ dt_bias, float* __restrict__ dtb,
                            int layer) {
    int c = threadIdx.x;            // 384
    int row0 = blockIdx.x * 4;
    int l0 = row0 & (SEQ - 1);
    const float* cw = convw + (size_t)layer * 4 * CDIM;
    float w0 = cw[c], w1 = cw[CDIM + c], w2 = cw[2 * CDIM + c], w3 = cw[3 * CDIM + c];
    float bb = convb[layer * CDIM + c];
    float v[7];
    #pragma unroll
    for (int i = 0; i < 7; i++) {
        int rr = row0 + i - 3;
        v[i] = (l0 + i - 3 >= 0) ? s2f(xbc[(size_t)rr * CDIM + c]) : 0.f;
    }
    #pragma unroll
    for (int j = 0; j < 4; j++) {
        float acc = bb + w0 * v[j] + w1 * v[j + 1] + w2 * v[j + 2] + w3 * v[j + 3];
        xcb[(size_t)(row0 + j) * CDIM + c] = f2b(silu(acc));
    }
    if (c < 128) {
        int r = c >> 5;
        int rem = c & 31;
        int hh = rem >> 3;
        int part = rem & 7;
        const short* hrow = hnb + (size_t)(row0 + r) * DM + part * 16;
        const short* wrow = wb + WB_IN + (size_t)layer * 82432 + (640 + hh) * 128 + part * 16;
        short8 hv0 = *reinterpret_cast<const short8*>(hrow);
        short8 hv1 = *reinterpret_cast<const short8*>(hrow + 8);
        short8 wv0 = *reinterpret_cast<const short8*>(wrow);
        short8 wv1 = *reinterpret_cast<const short8*>(wrow + 8);
        float s = 0.f;
        #pragma unroll
        for (int q = 0; q < 8; q++)
            s += s2f(hv0[q]) * s2f(wv0[q]) + s2f(hv1[q]) * s2f(wv1[q]);
        s += __shfl_xor(s, 1);
        s += __shfl_xor(s, 2);
        s += __shfl_xor(s, 4);
        if (part == 0) {
            float raw = s + dt_bias[layer * NH + hh];
            float dt = (raw > 20.f) ? raw : log1pf(expf(raw));
            dtb[(size_t)(row0 + r) * NH + hh] = dt;
        }
    }
}

// ---------------- fallback: chunk A (MFMA) ----------------
__global__ __launch_bounds__(256) void chunk_state_mfma(const short* __restrict__ xcb,
                                                        const float* __restrict__ dtb,
                                                        const float* __restrict__ A_log,
                                                        short* __restrict__ Slocb,
                                                        float* __restrict__ decay, int layer) {
    __shared__ short XTw[64 * 72];
    __shared__ short BT[64 * 72];
    __shared__ float wst[64];
    int bid = blockIdx.x;
    int c  = bid & (NCHUNK - 1);
    int hh = (bid >> 4) & (NH - 1);
    int b  = bid >> 6;
    int tid = threadIdx.x;
    int row0 = b * SEQ + c * CHUNK;
    float A = -expf(A_log[layer * NH + hh]);

    if (tid < CHUNK) {
        float dtv = dtb[(size_t)(row0 + tid) * NH + hh];
        float l = dtv * A;
        #pragma unroll
        for (int o = 1; o < 64; o <<= 1) { float v = __shfl_up(l, o); if (tid >= o) l += v; }
        float Ltot = __shfl(l, 63);
        wst[tid] = expf(Ltot - l) * dtv;
        if (tid == 63) decay[bid] = expf(Ltot);
    }
    __syncthreads();
    {
        int p = tid & 63;
        int tb0 = tid >> 6;
        #pragma unroll
        for (int i = 0; i < 2; i++) {
            int t0 = (tb0 + i * 4) * 8;
            short8 xv, bv;
            #pragma unroll
            for (int j = 0; j < 8; j++) {
                int t = t0 + j;
                const short* xr = xcb + (size_t)(row0 + t) * CDIM;
                xv[j] = f2b(s2f(xr[hh * HD + p]) * wst[t]);
                bv[j] = xr[DI + p];
            }
            *reinterpret_cast<short8*>(&XTw[p * 72 + t0]) = xv;
            *reinterpret_cast<short8*>(&BT[p * 72 + t0]) = bv;
        }
    }
    __syncthreads();

    int lane = tid & 63;
    int m = lane & 15;
    int kq = (lane >> 4) * 8;
    int w = tid >> 6;
    int a_off = (w * 16 + m) * 72 + kq;
    float4v acc[4];
    acc[0] = (float4v)0.f; acc[1] = (float4v)0.f; acc[2] = (float4v)0.f; acc[3] = (float4v)0.f;
    short8 a0 = *reinterpret_cast<const short8*>(&XTw[a_off]);
    short8 a1 = *reinterpret_cast<const short8*>(&XTw[a_off + 32]);
    #pragma unroll
    for (int nt = 0; nt < 4; nt++) {
        int bo = (nt * 16 + m) * 72 + kq;
        short8 b0 = *reinterpret_cast<const short8*>(&BT[bo]);
        short8 b1 = *reinterpret_cast<const short8*>(&BT[bo + 32]);
        acc[nt] = __builtin_amdgcn_mfma_f32_16x16x32_bf16(a0, b0, acc[nt], 0, 0, 0);
        acc[nt] = __builtin_amdgcn_mfma_f32_16x16x32_bf16(a1, b1, acc[nt], 0, 0, 0);
    }
    short* Sp = Slocb + (size_t)bid * (HD * DST);
    int tq = (lane >> 4) * 4;
    #pragma unroll
    for (int nt = 0; nt < 4; nt++) {
        #pragma unroll
        for (int r = 0; r < 4; r++) {
            int p = w * 16 + tq + r;
            int n = nt * 16 + m;
            Sp[p * DST + n] = f2b(acc[nt][r]);
        }
    }
}

// ---------------- fallback: chunk C (MFMA) + fused inter-chunk recurrence ----------------
__global__ __launch_bounds__(256) void chunk_out_mfma(const short* __restrict__ xcb,
                                                      const float* __restrict__ dtb,
                                                      const float* __restrict__ A_log,
                                                      const float* __restrict__ Dpw,
                                                      const short* __restrict__ Slocb,
                                                      const float* __restrict__ decay,
                                                      short* __restrict__ ybb, int layer) {
    __shared__ short Cb[64 * 72];
    __shared__ short Bb[64 * 72];
    __shared__ short XT[64 * 72];
    __shared__ short HT[64 * 72];
    __shared__ float Ls[64], dts[64];
    int bid = blockIdx.x;
    int c  = bid & (NCHUNK - 1);
    int hh = (bid >> 4) & (NH - 1);
    int b  = bid >> 6;
    int tid = threadIdx.x;
    int row0 = b * SEQ + c * CHUNK;
    int bh0 = bid & ~(NCHUNK - 1);
    float A = -expf(A_log[layer * NH + hh]);
    float Dph = Dpw[layer * NH + hh];

    if (tid < CHUNK) {
        float dtv = dtb[(size_t)(row0 + tid) * NH + hh];
        float l = dtv * A;
        #pragma unroll
        for (int o = 1; o < 64; o <<= 1) { float v = __shfl_up(l, o); if (tid >= o) l += v; }
        Ls[tid] = l;
        dts[tid] = dtv;
    }
    {
        float hreg[16];
        #pragma unroll
        for (int k = 0; k < 16; k++) hreg[k] = 0.f;
        for (int j = 0; j < c; j++) {
            float d = decay[bh0 + j];
            const short* Sp = Slocb + (size_t)(bh0 + j) * (HD * DST) + tid * 16;
            short8 s0 = *reinterpret_cast<const short8*>(Sp);
            short8 s1 = *reinterpret_cast<const short8*>(Sp + 8);
            #pragma unroll
            for (int k = 0; k < 8; k++) {
                hreg[k]     = d * hreg[k]     + s2f(s0[k]);
                hreg[8 + k] = d * hreg[8 + k] + s2f(s1[k]);
            }
        }
        int p = tid >> 2;
        int n0 = (tid & 3) * 16;
        short8 h0, h1;
        #pragma unroll
        for (int k = 0; k < 8; k++) { h0[k] = f2b(hreg[k]); h1[k] = f2b(hreg[8 + k]); }
        *reinterpret_cast<short8*>(&HT[p * 72 + n0]) = h0;
        *reinterpret_cast<short8*>(&HT[p * 72 + n0 + 8]) = h1;
    }
    {
        int p = tid & 63;
        int tb0 = tid >> 6;
        #pragma unroll
        for (int i = 0; i < 2; i++) {
            int t0 = (tb0 + i * 4) * 8;
            short8 xv;
            #pragma unroll
            for (int j = 0; j < 8; j++)
                xv[j] = xcb[(size_t)(row0 + t0 + j) * CDIM + hh * HD + p];
            *reinterpret_cast<short8*>(&XT[p * 72 + t0]) = xv;
        }
    }
    #pragma unroll
    for (int i = 0; i < 2; i++) {
        int idx = tid + i * 256;
        int t = idx >> 3, cb = (idx & 7) * 8;
        const short* xr = xcb + (size_t)(row0 + t) * CDIM;
        *reinterpret_cast<short8*>(&Bb[t * 72 + cb]) =
            *reinterpret_cast<const short8*>(&xr[DI + cb]);
        *reinterpret_cast<short8*>(&Cb[t * 72 + cb]) =
            *reinterpret_cast<const short8*>(&xr[DI + DST + cb]);
    }
    __syncthreads();

    int lane = tid & 63;
    int m = lane & 15;
    int kq = (lane >> 4) * 8;
    int w = tid >> 6;
    int tq = (lane >> 4) * 4;
    int a_off = (w * 16 + m) * 72 + kq;

    short8 ca0 = *reinterpret_cast<const short8*>(&Cb[a_off]);
    short8 ca1 = *reinterpret_cast<const short8*>(&Cb[a_off + 32]);

    float4v g[4], ir[4];
    #pragma unroll
    for (int i = 0; i < 4; i++) { g[i] = (float4v)0.f; ir[i] = (float4v)0.f; }
    #pragma unroll
    for (int st = 0; st < 4; st++) {
        int bo = (st * 16 + m) * 72 + kq;
        short8 b0 = *reinterpret_cast<const short8*>(&Bb[bo]);
        short8 b1 = *reinterpret_cast<const short8*>(&Bb[bo + 32]);
        g[st] = __builtin_amdgcn_mfma_f32_16x16x32_bf16(ca0, b0, g[st], 0, 0, 0);
        g[st] = __builtin_amdgcn_mfma_f32_16x16x32_bf16(ca1, b1, g[st], 0, 0, 0);
        short8 h0 = *reinterpret_cast<const short8*>(&HT[bo]);
        short8 h1 = *reinterpret_cast<const short8*>(&HT[bo + 32]);
        ir[st] = __builtin_amdgcn_mfma_f32_16x16x32_bf16(ca0, h0, ir[st], 0, 0, 0);
        ir[st] = __builtin_amdgcn_mfma_f32_16x16x32_bf16(ca1, h1, ir[st], 0, 0, 0);
    }
    __syncthreads();
    #pragma unroll
    for (int st = 0; st < 4; st++) {
        #pragma unroll
        for (int r = 0; r < 4; r++) {
            int t = w * 16 + tq + r;
            int s = st * 16 + m;
            float mv = 0.f;
            if (s <= t) mv = g[st][r] * expf(Ls[t] - Ls[s]) * dts[s];
            Bb[t * 72 + s] = f2b(mv);
        }
    }
    __syncthreads();
    float4v yi[4];
    #pragma unroll
    for (int i = 0; i < 4; i++) yi[i] = (float4v)0.f;
    short8 ma0 = *reinterpret_cast<const short8*>(&Bb[a_off]);
    short8 ma1 = *reinterpret_cast<const short8*>(&Bb[a_off + 32]);
    #pragma unroll
    for (int pt = 0; pt < 4; pt++) {
        int bo = (pt * 16 + m) * 72 + kq;
        short8 x0 = *reinterpret_cast<const short8*>(&XT[bo]);
        short8 x1 = *reinterpret_cast<const short8*>(&XT[bo + 32]);
        yi[pt] = __builtin_amdgcn_mfma_f32_16x16x32_bf16(ma0, x0, yi[pt], 0, 0, 0);
        yi[pt] = __builtin_amdgcn_mfma_f32_16x16x32_bf16(ma1, x1, yi[pt], 0, 0, 0);
    }
    #pragma unroll
    for (int r = 0; r < 4; r++) {
        int t = w * 16 + tq + r;
        float et = expf(Ls[t]);
        short* yr = ybb + (size_t)(row0 + t) * DI + hh * HD;
        #pragma unroll
        for (int pt = 0; pt < 4; pt++) {
            int p = pt * 16 + m;
            float xv = s2f(XT[p * 72 + t]);
            yr[p] = f2b(yi[pt][r] + et * ir[pt][r] + Dph * xv);
        }
    }
}

// ---------------- fallback: out_proj + gate/RMSNorm + residual (+LN / +fc2) ----------------
__global__ __launch_bounds__(512) void outproj_gate_mfma(const short* __restrict__ ybb,
                                                         const short* __restrict__ zb,
                                                         const float* __restrict__ rmsw,
                                                         const short* __restrict__ wb,
                                                         const float* __restrict__ lnw2,
                                                         const float* __restrict__ lnb2,
                                                         float* __restrict__ h,
                                                         short* __restrict__ hnb,
                                                         const float* __restrict__ fc2_b1,
                                                         const float* __restrict__ fc2_W2,
                                                         const float* __restrict__ fc2_b2,
                                                         float* __restrict__ outp,
                                                         int layer, int do_fc2) {
    __shared__ __align__(16) short As[32 * 264];
    __shared__ __align__(16) short Bt[2][128 * 72];
    __shared__ float w2s[768];
    int tid = threadIdx.x;
    int lane = tid & 63;
    int m = lane & 15;
    int quad = lane >> 4;
    int kq = quad * 8;
    int w = tid >> 6;
    int mrow = (w & 1) * 16;
    int ngrp = w >> 1;
    int row0 = blockIdx.x * 32;
    const short* wt = wb + WB_OUT + (size_t)layer * 32768;
    if (do_fc2)
        for (int i = tid; i < 768; i += 512) w2s[i] = fc2_W2[i];
    {
        int r = tid >> 4, j = tid & 15;
        const short* yr = ybb + (size_t)(row0 + r) * DI + j * 16;
        const short* zr = zb + (size_t)(row0 + r) * DI + j * 16;
        short8 y0 = *reinterpret_cast<const short8*>(yr);
        short8 y1 = *reinterpret_cast<const short8*>(yr + 8);
        short8 z0 = *reinterpret_cast<const short8*>(zr);
        short8 z1 = *reinterpret_cast<const short8*>(zr + 8);
        float v[16]; float s2 = 0.f;
        #pragma unroll
        for (int q = 0; q < 8; q++) {
            v[q]     = s2f(y0[q]) * silu(s2f(z0[q]));
            v[8 + q] = s2f(y1[q]) * silu(s2f(z1[q]));
        }
        #pragma unroll
        for (int q = 0; q < 16; q++) s2 += v[q] * v[q];
        #pragma unroll
        for (int o = 1; o < 16; o <<= 1) s2 += __shfl_xor(s2, o);
        float rs = rsqrtf(s2 * (1.f / 256.f) + 1e-5f);
        const float* rw = rmsw + layer * DI + j * 16;
        short8 a0, a1;
        #pragma unroll
        for (int q = 0; q < 8; q++) {
            a0[q] = f2b(v[q] * rs * rw[q]);
            a1[q] = f2b(v[8 + q] * rs * rw[8 + q]);
        }
        *reinterpret_cast<short8*>(&As[r * 264 + j * 16]) = a0;
        *reinterpret_cast<short8*>(&As[r * 264 + j * 16 + 8]) = a1;
    }
    {
        int n = tid >> 2, kk = (tid & 3) * 16;
        *reinterpret_cast<short8*>(&Bt[0][n * 72 + kk]) =
            *reinterpret_cast<const short8*>(&wt[n * 256 + kk]);
        *reinterpret_cast<short8*>(&Bt[0][n * 72 + kk + 8]) =
            *reinterpret_cast<const short8*>(&wt[n * 256 + kk + 8]);
    }
    __syncthreads();
    float4v acc[2];
    acc[0] = (float4v)0.f; acc[1] = (float4v)0.f;
    int buf = 0;
    for (int kt = 0; kt < 4; kt++) {
        if (kt < 3) {
            int n = tid >> 2, kk = (tid & 3) * 16;
            *reinterpret_cast<short8*>(&Bt[buf ^ 1][n * 72 + kk]) =
                *reinterpret_cast<const short8*>(&wt[n * 256 + (kt + 1) * 64 + kk]);
            *reinterpret_cast<short8*>(&Bt[buf ^ 1][n * 72 + kk + 8]) =
                *reinterpret_cast<const short8*>(&wt[n * 256 + (kt + 1) * 64 + kk + 8]);
        }
        short8 a0 = *reinterpret_cast<const short8*>(&As[(mrow + m) * 264 + kt * 64 + kq]);
        short8 a1 = *reinterpret_cast<const short8*>(&As[(mrow + m) * 264 + kt * 64 + kq + 32]);
        #pragma unroll
        for (int nt = 0; nt < 2; nt++) {
            int bo = (ngrp * 32 + nt * 16 + m) * 72 + kq;
            short8 b0 = *reinterpret_cast<const short8*>(&Bt[buf][bo]);
            short8 b1 = *reinterpret_cast<const short8*>(&Bt[buf][bo + 32]);
            acc[nt] = __builtin_amdgcn_mfma_f32_16x16x32_bf16(a0, b0, acc[nt], 0, 0, 0);
            acc[nt] = __builtin_amdgcn_mfma_f32_16x16x32_bf16(a1, b1, acc[nt], 0, 0, 0);
        }
        __syncthreads();
        buf ^= 1;
    }
    float* hs = (float*)As;
    #pragma unroll
    for (int nt = 0; nt < 2; nt++) {
        int col = ngrp * 32 + nt * 16 + m;
        #pragma unroll
        for (int r = 0; r < 4; r++)
            hs[(mrow + quad * 4 + r) * 132 + col] = acc[nt][r];
    }
    __syncthreads();
    int er = tid >> 4, ej = tid & 15;
    int erow = row0 + er;
    float vals[8];
    float s1 = 0.f, s2v = 0.f;
    {
        const float* hsrc = h + (size_t)erow * DM + ej * 8;
        float4 h0 = *(const float4*)hsrc;
        float4 h1 = *(const float4*)(hsrc + 4);
        const float* hrow = &hs[er * 132 + ej * 8];
        float4 q0 = *(const float4*)hrow;
        float4 q1 = *(const float4*)(hrow + 4);
        vals[0] = h0.x + q0.x; vals[1] = h0.y + q0.y; vals[2] = h0.z + q0.z; vals[3] = h0.w + q0.w;
        vals[4] = h1.x + q1.x; vals[5] = h1.y + q1.y; vals[6] = h1.z + q1.z; vals[7] = h1.w + q1.w;
        #pragma unroll
        for (int i = 0; i < 8; i++) { s1 += vals[i]; s2v += vals[i] * vals[i]; }
    }
    if (!do_fc2) {
        #pragma unroll
        for (int o = 1; o < 16; o <<= 1) { s1 += __shfl_xor(s1, o); s2v += __shfl_xor(s2v, o); }
        float* hdst = h + (size_t)erow * DM + ej * 8;
        *(float4*)hdst = make_float4(vals[0], vals[1], vals[2], vals[3]);
        *(float4*)(hdst + 4) = make_float4(vals[4], vals[5], vals[6], vals[7]);
        float mu = s1 * (1.f / 128.f);
        float rs2 = rsqrtf(s2v * (1.f / 128.f) - mu * mu + 1e-5f);
        const float* lw = lnw2 + ej * 8;
        const float* lb = lnb2 + ej * 8;
        short8 a0;
        #pragma unroll
        for (int i = 0; i < 8; i++) a0[i] = f2b((vals[i] - mu) * rs2 * lw[i] + lb[i]);
        *reinterpret_cast<short8*>(hnb + (size_t)erow * DM + ej * 8) = a0;
        return;
    }
    __syncthreads();
    short* As2 = (short*)As;
    {
        short8 ap;
        #pragma unroll
        for (int i = 0; i < 8; i++) ap[i] = f2b(vals[i]);
        *reinterpret_cast<short8*>(&As2[er * 136 + ej * 8]) = ap;
    }
    const short* wtf = wb + WB_FC2;
    short* Bt2 = (short*)Bt;
    {
        int n = tid >> 2, kk = (tid & 3) * 32;
        #pragma unroll
        for (int i = 0; i < 4; i++)
            *reinterpret_cast<short8*>(&Bt2[n * 136 + kk + i * 8]) =
                *reinterpret_cast<const short8*>(&wtf[n * 128 + kk + i * 8]);
    }
    __syncthreads();
    float4v acc2[2];
    acc2[0] = (float4v)0.f; acc2[1] = (float4v)0.f;
    #pragma unroll
    for (int kt = 0; kt < 2; kt++) {
        int k0 = kt * 64;
        short8 a0 = *reinterpret_cast<const short8*>(&As2[(mrow + m) * 136 + k0 + kq]);
        short8 a1 = *reinterpret_cast<const short8*>(&As2[(mrow + m) * 136 + k0 + kq + 32]);
        #pragma unroll
        for (int nt = 0; nt < 2; nt++) {
            int bo = (ngrp * 32 + nt * 16 + m) * 136 + k0 + kq;
            short8 b0 = *reinterpret_cast<const short8*>(&Bt2[bo]);
            short8 b1 = *reinterpret_cast<const short8*>(&Bt2[bo + 32]);
            acc2[nt] = __builtin_amdgcn_mfma_f32_16x16x32_bf16(a0, b0, acc2[nt], 0, 0, 0);
            acc2[nt] = __builtin_amdgcn_mfma_f32_16x16x32_bf16(a1, b1, acc2[nt], 0, 0, 0);
        }
    }
    __syncthreads();
    float* h2s = (float*)As;
    #pragma unroll
    for (int nt = 0; nt < 2; nt++) {
        int col = ngrp * 32 + nt * 16 + m;
        float bv = fc2_b1[col];
        #pragma unroll
        for (int r = 0; r < 4; r++) {
            float o = acc2[nt][r] + bv;
            h2s[(mrow + quad * 4 + r) * 132 + col] = (o > 0.f) ? o : 0.1f * o;
        }
    }
    __syncthreads();
    if (tid < 384) {
        int r = tid / 12, q = tid % 12, cc = q >> 1, part = q & 1;
        float a2 = 0.f;
        #pragma unroll 8
        for (int k = 0; k < 64; k++)
            a2 += h2s[r * 132 + part * 64 + k] * w2s[(part * 64 + k) * 6 + cc];
        a2 += __shfl_xor(a2, 1);
        if (!part) outp[(size_t)(row0 + r) * 6 + cc] = fc2_b2[cc] + a2;
    }
}

// ============================================================
// Cooperative per-layer megakernel: inproj -> conv+dt -> chunk_state -> chunk_out -> outproj
// grid 512 x 512 threads (2 blocks/CU), grid.sync() between phases.
// ============================================================
__global__ __launch_bounds__(512, 4) void layer_mega(
        short* __restrict__ hnb, const short* __restrict__ wb,
        short* __restrict__ zb, short* __restrict__ xbc, short* __restrict__ xcb,
        float* __restrict__ dtb, const float* __restrict__ dt_bias,
        const float* __restrict__ convw, const float* __restrict__ convb,
        const float* __restrict__ A_log, const float* __restrict__ Dpw,
        short* __restrict__ Slocb, float* __restrict__ decay,
        short* __restrict__ ybb, const float* __restrict__ rmsw,
        const float* __restrict__ lnw2, const float* __restrict__ lnb2,
        float* __restrict__ h,
        const float* __restrict__ fc2_b1, const float* __restrict__ fc2_W2,
        const float* __restrict__ fc2_b2, float* __restrict__ outp,
        int layer) {
    cg::grid_group grid = cg::this_grid();
    __shared__ __align__(16) char smem[56832];
    int tid = threadIdx.x;
    int bx = blockIdx.x;
    int do_fc2 = (layer == 1);

    // ===== Phase A: in_proj (full-K single-barrier; 1280 vtiles over 512 blocks) =====
    {
        short* As = (short*)smem;              // [64][136]
        short* Bt = (short*)(smem + 17408);    // [128][136]
        const short* wt = wb + WB_IN + (size_t)layer * 82432;
        int lane = tid & 63, m = lane & 15, kq = (lane >> 4) * 8, w = tid >> 6;
        int mrow = (w & 3) * 16, ngrp = w >> 2;
        for (int vb = bx; vb < 1280; vb += 512) {
            int row0 = (vb & 255) * 64;
            int ncol0 = (vb >> 8) * 128;
            const short* srcA = hnb + (size_t)row0 * DM;
            #pragma unroll
            for (int i = 0; i < 2; i++) {
                int u = i * 512 + tid;
                *reinterpret_cast<short8*>(&As[(u >> 4) * 136 + (u & 15) * 8]) =
                    *reinterpret_cast<const short8*>(&srcA[u * 8]);
            }
            #pragma unroll
            for (int i = 0; i < 4; i++) {
                int u = i * 512 + tid;
                int n = u >> 4, c8 = (u & 15) * 8;
                *reinterpret_cast<short8*>(&Bt[n * 136 + c8]) =
                    *reinterpret_cast<const short8*>(&wt[(ncol0 + n) * 128 + c8]);
            }
            __syncthreads();
            float4v acc[4];
            acc[0] = (float4v)0.f; acc[1] = (float4v)0.f; acc[2] = (float4v)0.f; acc[3] = (float4v)0.f;
            #pragma unroll
            for (int ks = 0; ks < 4; ks++) {
                short8 a = *reinterpret_cast<const short8*>(&As[(mrow + m) * 136 + ks * 32 + kq]);
                #pragma unroll
                for (int nt = 0; nt < 4; nt++) {
                    short8 b = *reinterpret_cast<const short8*>(
                        &Bt[(ngrp * 64 + nt * 16 + m) * 136 + ks * 32 + kq]);
                    acc[nt] = __builtin_amdgcn_mfma_f32_16x16x32_bf16(a, b, acc[nt], 0, 0, 0);
                }
            }
            int colbase = ncol0 + ngrp * 64;
            if (ncol0 < DI) {
                #pragma unroll
                for (int nt = 0; nt < 4; nt++) {
                    int col = colbase + nt * 16 + m;
                    #pragma unroll
                    for (int r = 0; r < 4; r++) {
                        int row = row0 + mrow + (lane >> 4) * 4 + r;
                        zb[(size_t)row * DI + col] = f2b(acc[nt][r]);
                    }
                }
            } else {
                int xbase = colbase - DI;
                #pragma unroll
                for (int nt = 0; nt < 4; nt++) {
                    int col = xbase + nt * 16 + m;
                    #pragma unroll
                    for (int r = 0; r < 4; r++) {
                        int row = row0 + mrow + (lane >> 4) * 4 + r;
                        xbc[(size_t)row * CDIM + col] = f2b(acc[nt][r]);
                    }
                }
            }
            __syncthreads();
        }
    }
    __threadfence();
    grid.sync();

    // ===== Phase B: causal conv(4)+SiLU + dt GEMV (4096 row-groups over 512 blocks) =====
    {
        int c = tid;
        float w0 = 0.f, w1 = 0.f, w2 = 0.f, w3 = 0.f, bb = 0.f;
        const float* cw = convw + (size_t)layer * 4 * CDIM;
        if (c < CDIM) {
            w0 = cw[c]; w1 = cw[CDIM + c]; w2 = cw[2 * CDIM + c]; w3 = cw[3 * CDIM + c];
            bb = convb[layer * CDIM + c];
        }
        for (int g = bx; g < NROWS / 4; g += 512) {
            int row0 = g * 4;
            int l0 = row0 & (SEQ - 1);
            if (c < CDIM) {
                float v[7];
                #pragma unroll
                for (int i = 0; i < 7; i++) {
                    int rr = row0 + i - 3;
                    v[i] = (l0 + i - 3 >= 0) ? s2f(xbc[(size_t)rr * CDIM + c]) : 0.f;
                }
                #pragma unroll
                for (int j = 0; j < 4; j++) {
                    float a = bb + w0 * v[j] + w1 * v[j + 1] + w2 * v[j + 2] + w3 * v[j + 3];
                    xcb[(size_t)(row0 + j) * CDIM + c] = f2b(silu(a));
                }
            }
            if (c < 128) {
                int r = c >> 5, rem = c & 31;
                int hh = rem >> 3, part = rem & 7;
                const short* hrow = hnb + (size_t)(row0 + r) * DM + part * 16;
                const short* wrow = wb + WB_IN + (size_t)layer * 82432 + (640 + hh) * 128 + part * 16;
                short8 hv0 = *reinterpret_cast<const short8*>(hrow);
                short8 hv1 = *reinterpret_cast<const short8*>(hrow + 8);
                short8 wv0 = *reinterpret_cast<const short8*>(wrow);
                short8 wv1 = *reinterpret_cast<const short8*>(wrow + 8);
                float s = 0.f;
                #pragma unroll
                for (int q = 0; q < 8; q++)
                    s += s2f(hv0[q]) * s2f(wv0[q]) + s2f(hv1[q]) * s2f(wv1[q]);
                s += __shfl_xor(s, 1);
                s += __shfl_xor(s, 2);
                s += __shfl_xor(s, 4);
                if (part == 0) {
                    float raw = s + dt_bias[layer * NH + hh];
                    float dt = (raw > 20.f) ? raw : log1pf(expf(raw));
                    dtb[(size_t)(row0 + r) * NH + hh] = dt;
                }
            }
        }
    }
    __threadfence();
    grid.sync();

    // ===== Phase C: chunk_state (1024 vbids, 2 iterations/block) =====
    {
        short* XTw = (short*)smem;             // [64][72]
        short* BT  = (short*)(smem + 9216);    // [64][72]
        float* wst = (float*)(smem + 18432);   // [64]
        for (int it = 0; it < 2; it++) {
            int bid = bx + it * 512;
            int c  = bid & (NCHUNK - 1);
            int hh = (bid >> 4) & (NH - 1);
            int b  = bid >> 6;
            int row0 = b * SEQ + c * CHUNK;
            float A = -expf(A_log[layer * NH + hh]);
            if (tid < CHUNK) {
                float dtv = dtb[(size_t)(row0 + tid) * NH + hh];
                float l = dtv * A;
                #pragma unroll
                for (int o = 1; o < 64; o <<= 1) { float v = __shfl_up(l, o); if (tid >= o) l += v; }
                float Ltot = __shfl(l, 63);
                wst[tid] = expf(Ltot - l) * dtv;
                if (tid == 63) decay[bid] = expf(Ltot);
            }
            __syncthreads();
            {
                int p = tid & 63;
                int t0 = (tid >> 6) * 8;
                short8 xv, bv;
                #pragma unroll
                for (int j = 0; j < 8; j++) {
                    int t = t0 + j;
                    const short* xr = xcb + (size_t)(row0 + t) * CDIM;
                    xv[j] = f2b(s2f(xr[hh * HD + p]) * wst[t]);
                    bv[j] = xr[DI + p];
                }
                *reinterpret_cast<short8*>(&XTw[p * 72 + t0]) = xv;
                *reinterpret_cast<short8*>(&BT[p * 72 + t0]) = bv;
            }
            __syncthreads();
            if (tid < 256) {
                int lane = tid & 63;
                int m = lane & 15;
                int kq = (lane >> 4) * 8;
                int w = tid >> 6;
                int a_off = (w * 16 + m) * 72 + kq;
                float4v acc[4];
                acc[0] = (float4v)0.f; acc[1] = (float4v)0.f; acc[2] = (float4v)0.f; acc[3] = (float4v)0.f;
                short8 a0 = *reinterpret_cast<const short8*>(&XTw[a_off]);
                short8 a1 = *reinterpret_cast<const short8*>(&XTw[a_off + 32]);
                #pragma unroll
                for (int nt = 0; nt < 4; nt++) {
                    int bo = (nt * 16 + m) * 72 + kq;
                    short8 b0 = *reinterpret_cast<const short8*>(&BT[bo]);
                    short8 b1 = *reinterpret_cast<const short8*>(&BT[bo + 32]);
                    acc[nt] = __builtin_amdgcn_mfma_f32_16x16x32_bf16(a0, b0, acc[nt], 0, 0, 0);
                    acc[nt] = __builtin_amdgcn_mfma_f32_16x16x32_bf16(a1, b1, acc[nt], 0, 0, 0);
                }
                short* Sp = Slocb + (size_t)bid * (HD * DST);
                int tq = (lane >> 4) * 4;
                #pragma unroll
                for (int nt = 0; nt < 4; nt++) {
                    #pragma unroll
                    for (int r = 0; r < 4; r++) {
                        int p = w * 16 + tq + r;
                        int n = nt * 16 + m;
                        Sp[p * DST + n] = f2b(acc[nt][r]);
                    }
                }
            }
            __syncthreads();
        }
    }
    __threadfence();
    grid.sync();

    // ===== Phase D: chunk_out + in-block recurrence (1024 vbids, 2 iterations/block) =====
    {
        short* Cb = (short*)smem;              // [64][72]
        short* Bb = (short*)(smem + 9216);     // [64][72]
        short* XT = (short*)(smem + 18432);    // [64][72]
        short* HT = (short*)(smem + 27648);    // [64][72]
        float* Ls = (float*)(smem + 36864);    // [64]
        float* dts = (float*)(smem + 37120);   // [64]
        for (int it = 0; it < 2; it++) {
            int bid = bx + it * 512;
            int c  = bid & (NCHUNK - 1);
            int hh = (bid >> 4) & (NH - 1);
            int b  = bid >> 6;
            int row0 = b * SEQ + c * CHUNK;
            int bh0 = bid & ~(NCHUNK - 1);
            float A = -expf(A_log[layer * NH + hh]);
            float Dph = Dpw[layer * NH + hh];
            if (tid < CHUNK) {
                float dtv = dtb[(size_t)(row0 + tid) * NH + hh];
                float l = dtv * A;
                #pragma unroll
                for (int o = 1; o < 64; o <<= 1) { float v = __shfl_up(l, o); if (tid >= o) l += v; }
                Ls[tid] = l;
                dts[tid] = dtv;
            }
            {   // inter-chunk recurrence: 512 threads x 8 state elems
                float hreg[8];
                #pragma unroll
                for (int k = 0; k < 8; k++) hreg[k] = 0.f;
                for (int j = 0; j < c; j++) {
                    float d = decay[bh0 + j];
                    const short* Sp = Slocb + (size_t)(bh0 + j) * (HD * DST) + tid * 8;
                    short8 s0 = *reinterpret_cast<const short8*>(Sp);
                    #pragma unroll
                    for (int k = 0; k < 8; k++) hreg[k] = d * hreg[k] + s2f(s0[k]);
                }
                short8 h0;
                #pragma unroll
                for (int k = 0; k < 8; k++) h0[k] = f2b(hreg[k]);
                int p = tid >> 3, n0 = (tid & 7) * 8;
                *reinterpret_cast<short8*>(&HT[p * 72 + n0]) = h0;
            }
            {   // XT staging: 512 threads
                int p = tid & 63;
                int t0 = (tid >> 6) * 8;
                short8 xv;
                #pragma unroll
                for (int j = 0; j < 8; j++)
                    xv[j] = xcb[(size_t)(row0 + t0 + j) * CDIM + hh * HD + p];
                *reinterpret_cast<short8*>(&XT[p * 72 + t0]) = xv;
            }
            {   // Bb/Cb staging: 512 threads
                int t = tid >> 3, cb = (tid & 7) * 8;
                const short* xr = xcb + (size_t)(row0 + t) * CDIM;
                *reinterpret_cast<short8*>(&Bb[t * 72 + cb]) =
                    *reinterpret_cast<const short8*>(&xr[DI + cb]);
                *reinterpret_cast<short8*>(&Cb[t * 72 + cb]) =
                    *reinterpret_cast<const short8*>(&xr[DI + DST + cb]);
            }
            __syncthreads();
            int lane = tid & 63;
            int m = lane & 15;
            int kq = (lane >> 4) * 8;
            int w = tid >> 6;
            int tq = (lane >> 4) * 4;
            int a_off = ((w & 3) * 16 + m) * 72 + kq;
            float4v g[4], ir[4], yi[4];
            #pragma unroll
            for (int i = 0; i < 4; i++) { g[i] = (float4v)0.f; ir[i] = (float4v)0.f; yi[i] = (float4v)0.f; }
            if (tid < 256) {
                short8 ca0 = *reinterpret_cast<const short8*>(&Cb[a_off]);
                short8 ca1 = *reinterpret_cast<const short8*>(&Cb[a_off + 32]);
                #pragma unroll
                for (int st = 0; st < 4; st++) {
                    int bo = (st * 16 + m) * 72 + kq;
                    short8 b0 = *reinterpret_cast<const short8*>(&Bb[bo]);
                    short8 b1 = *reinterpret_cast<const short8*>(&Bb[bo + 32]);
                    g[st] = __builtin_amdgcn_mfma_f32_16x16x32_bf16(ca0, b0, g[st], 0, 0, 0);
                    g[st] = __builtin_amdgcn_mfma_f32_16x16x32_bf16(ca1, b1, g[st], 0, 0, 0);
                    short8 h0 = *reinterpret_cast<const short8*>(&HT[bo]);
                    short8 h1 = *reinterpret_cast<const short8*>(&HT[bo + 32]);
                    ir[st] = __builtin_amdgcn_mfma_f32_16x16x32_bf16(ca0, h0, ir[st], 0, 0, 0);
                    ir[st] = __builtin_amdgcn_mfma_f32_16x16x32_bf16(ca1, h1, ir[st], 0, 0, 0);
                }
            }
            __syncthreads();
            if (tid < 256) {
                #pragma unroll
                for (int st = 0; st < 4; st++) {
                    #pragma unroll
                    for (int r = 0; r < 4; r++) {
                        int t = w * 16 + tq + r;
                        int s = st * 16 + m;
                        float mv = 0.f;
                        if (s <= t) mv = g[st][r] * expf(Ls[t] - Ls[s]) * dts[s];
                        Bb[t * 72 + s] = f2b(mv);
                    }
                }
            }
            __syncthreads();
            if (tid < 256) {
                short8 ma0 = *reinterpret_cast<const short8*>(&Bb[a_off]);
                short8 ma1 = *reinterpret_cast<const short8*>(&Bb[a_off + 32]);
                #pragma unroll
                for (int pt = 0; pt < 4; pt++) {
                    int bo = (pt * 16 + m) * 72 + kq;
                    short8 x0 = *reinterpret_cast<const short8*>(&XT[bo]);
                    short8 x1 = *reinterpret_cast<const short8*>(&XT[bo + 32]);
                    yi[pt] = __builtin_amdgcn_mfma_f32_16x16x32_bf16(ma0, x0, yi[pt], 0, 0, 0);
                    yi[pt] = __builtin_amdgcn_mfma_f32_16x16x32_bf16(ma1, x1, yi[pt], 0, 0, 0);
                }
                #pragma unroll
                for (int r = 0; r < 4; r++) {
                    int t = w * 16 + tq + r;
                    float et = expf(Ls[t]);
                    short* yr = ybb + (size_t)(row0 + t) * DI + hh * HD;
                    #pragma unroll
                    for (int pt = 0; pt < 4; pt++) {
                        int p = pt * 16 + m;
                        float xv = s2f(XT[p * 72 + t]);
                        yr[p] = f2b(yi[pt][r] + et * ir[pt][r] + Dph * xv);
                    }
                }
            }
            __syncthreads();
        }
    }
    __threadfence();
    grid.sync();

    // ===== Phase E: out_proj + gate/RMS + residual (+LN / +fc2) =====
    {
        short* As = (short*)smem;              // [32][264]; overlays hs/As2/h2s
        short* BtE = (short*)(smem + 16896);   // [2][128*72]; overlay Bt2
        float* w2s = (float*)(smem + 53760);   // [768]
        int lane = tid & 63;
        int m = lane & 15;
        int quad = lane >> 4;
        int kq = quad * 8;
        int w = tid >> 6;
        int mrow = (w & 1) * 16;
        int ngrp = w >> 1;
        int row0 = bx * 32;
        const short* wt = wb + WB_OUT + (size_t)layer * 32768;
        if (do_fc2)
            for (int i = tid; i < 768; i += 512) w2s[i] = fc2_W2[i];
        {
            int r = tid >> 4, j = tid & 15;
            const short* yr = ybb + (size_t)(row0 + r) * DI + j * 16;
            const short* zr = zb + (size_t)(row0 + r) * DI + j * 16;
            short8 y0 = *reinterpret_cast<const short8*>(yr);
            short8 y1 = *reinterpret_cast<const short8*>(yr + 8);
            short8 z0 = *reinterpret_cast<const short8*>(zr);
            short8 z1 = *reinterpret_cast<const short8*>(zr + 8);
            float v[16]; float s2 = 0.f;
            #pragma unroll
            for (int q = 0; q < 8; q++) {
                v[q]     = s2f(y0[q]) * silu(s2f(z0[q]));
                v[8 + q] = s2f(y1[q]) * silu(s2f(z1[q]));
            }
            #pragma unroll
            for (int q = 0; q < 16; q++) s2 += v[q] * v[q];
            #pragma unroll
            for (int o = 1; o < 16; o <<= 1) s2 += __shfl_xor(s2, o);
            float rs = rsqrtf(s2 * (1.f / 256.f) + 1e-5f);
            const float* rw = rmsw + layer * DI + j * 16;
            short8 a0, a1;
            #pragma unroll
            for (int q = 0; q < 8; q++) {
                a0[q] = f2b(v[q] * rs * rw[q]);
                a1[q] = f2b(v[8 + q] * rs * rw[8 + q]);
            }
            *reinterpret_cast<short8*>(&As[r * 264 + j * 16]) = a0;
            *reinterpret_cast<short8*>(&As[r * 264 + j * 16 + 8]) = a1;
        }
        {
            int n = tid >> 2, kk = (tid & 3) * 16;
            *reinterpret_cast<short8*>(&BtE[n * 72 + kk]) =
                *reinterpret_cast<const short8*>(&wt[n * 256 + kk]);
            *reinterpret_cast<short8*>(&BtE[n * 72 + kk + 8]) =
                *reinterpret_cast<const short8*>(&wt[n * 256 + kk + 8]);
        }
        __syncthreads();
        float4v acc[2];
        acc[0] = (float4v)0.f; acc[1] = (float4v)0.f;
        int buf = 0;
        for (int kt = 0; kt < 4; kt++) {
            if (kt < 3) {
                int n = tid >> 2, kk = (tid & 3) * 16;
                *reinterpret_cast<short8*>(&BtE[(buf ^ 1) * 9216 + n * 72 + kk]) =
                    *reinterpret_cast<const short8*>(&wt[n * 256 + (kt + 1) * 64 + kk]);
                *reinterpret_cast<short8*>(&BtE[(buf ^ 1) * 9216 + n * 72 + kk + 8]) =
                    *reinterpret_cast<const short8*>(&wt[n * 256 + (kt + 1) * 64 + kk + 8]);
            }
            short8 a0 = *reinterpret_cast<const short8*>(&As[(mrow + m) * 264 + kt * 64 + kq]);
            short8 a1 = *reinterpret_cast<const short8*>(&As[(mrow + m) * 264 + kt * 64 + kq + 32]);
            #pragma unroll
            for (int nt = 0; nt < 2; nt++) {
                int bo = (ngrp * 32 + nt * 16 + m) * 72 + kq;
                short8 b0 = *reinterpret_cast<const short8*>(&BtE[buf * 9216 + bo]);
                short8 b1 = *reinterpret_cast<const short8*>(&BtE[buf * 9216 + bo + 32]);
                acc[nt] = __builtin_amdgcn_mfma_f32_16x16x32_bf16(a0, b0, acc[nt], 0, 0, 0);
                acc[nt] = __builtin_amdgcn_mfma_f32_16x16x32_bf16(a1, b1, acc[nt], 0, 0, 0);
            }
            __syncthreads();
            buf ^= 1;
        }
        float* hs = (float*)As;
        #pragma unroll
        for (int nt = 0; nt < 2; nt++) {
            int col = ngrp * 32 + nt * 16 + m;
            #pragma unroll
            for (int r = 0; r < 4; r++)
                hs[(mrow + quad * 4 + r) * 132 + col] = acc[nt][r];
        }
        __syncthreads();
        int er = tid >> 4, ej = tid & 15;
        int erow = row0 + er;
        float vals[8];
        float s1 = 0.f, s2v = 0.f;
        {
            const float* hsrc = h + (size_t)erow * DM + ej * 8;
            float4 h0 = *(const float4*)hsrc;
            float4 h1 = *(const float4*)(hsrc + 4);
            const float* hrow = &hs[er * 132 + ej * 8];
            float4 q0 = *(const float4*)hrow;
            float4 q1 = *(const float4*)(hrow + 4);
            vals[0] = h0.x + q0.x; vals[1] = h0.y + q0.y; vals[2] = h0.z + q0.z; vals[3] = h0.w + q0.w;
            vals[4] = h1.x + q1.x; vals[5] = h1.y + q1.y; vals[6] = h1.z + q1.z; vals[7] = h1.w + q1.w;
            #pragma unroll
            for (int i = 0; i < 8; i++) { s1 += vals[i]; s2v += vals[i] * vals[i]; }
        }
        if (!do_fc2) {
            #pragma unroll
            for (int o = 1; o < 16; o <<= 1) { s1 += __shfl_xor(s1, o); s2v += __shfl_xor(s2v, o); }
            float* hdst = h + (size_t)erow * DM + ej * 8;
            *(float4*)hdst = make_float4(vals[0], vals[1], vals[2], vals[3]);
            *(float4*)(hdst + 4) = make_float4(vals[4], vals[5], vals[6], vals[7]);
            float mu = s1 * (1.f / 128.f);
            float rs2 = rsqrtf(s2v * (1.f / 128.f) - mu * mu + 1e-5f);
            const float* lw = lnw2 + ej * 8;
            const float* lb = lnb2 + ej * 8;
            short8 a0;
            #pragma unroll
            for (int i = 0; i < 8; i++) a0[i] = f2b((vals[i] - mu) * rs2 * lw[i] + lb[i]);
            *reinterpret_cast<short8*>(hnb + (size_t)erow * DM + ej * 8) = a0;
            return;
        }
        __syncthreads();
        short* As2 = (short*)As;
        {
            short8 ap;
            #pragma unroll
            for (int i = 0; i < 8; i++) ap[i] = f2b(vals[i]);
            *reinterpret_cast<short8*>(&As2[er * 136 + ej * 8]) = ap;
        }
        const short* wtf = wb + WB_FC2;
        short* Bt2 = BtE;
        {
            int n = tid >> 2, kk = (tid & 3) * 32;
            #pragma unroll
            for (int i = 0; i < 4; i++)
                *reinterpret_cast<short8*>(&Bt2[n * 136 + kk + i * 8]) =
                    *reinterpret_cast<const short8*>(&wtf[n * 128 + kk + i * 8]);
        }
        __syncthreads();
        float4v acc2[2];
        acc2[0] = (float4v)0.f; acc2[1] = (float4v)0.f;
        #pragma unroll
        for (int kt = 0; kt < 2; kt++) {
            int k0 = kt * 64;
            short8 a0 = *reinterpret_cast<const short8*>(&As2[(mrow + m) * 136 + k0 + kq]);
            short8 a1 = *reinterpret_cast<const short8*>(&As2[(mrow + m) * 136 + k0 + kq + 32]);
            #pragma unroll
            for (int nt = 0; nt < 2; nt++) {
                int bo = (ngrp * 32 + nt * 16 + m) * 136 + k0 + kq;
                short8 b0 = *reinterpret_cast<const short8*>(&Bt2[bo]);
                short8 b1 = *reinterpret_cast<const short8*>(&Bt2[bo + 32]);
                acc2[nt] = __builtin_amdgcn_mfma_f32_16x16x32_bf16(a0, b0, acc2[nt], 0, 0, 0);
                acc2[nt] = __builtin_amdgcn_mfma_f32_16x16x32_bf16(a1, b1, acc2[nt], 0, 0, 0);
            }
        }
        __syncthreads();
        float* h2s = (float*)As;
        #pragma unroll
        for (int nt = 0; nt < 2; nt++) {
            int col = ngrp * 32 + nt * 16 + m;
            float bv = fc2_b1[col];
            #pragma unroll
            for (int r = 0; r < 4; r++) {
                float o = acc2[nt][r] + bv;
                h2s[(mrow + quad * 4 + r) * 132 + col] = (o > 0.f) ? o : 0.1f * o;
            }
        }
        __syncthreads();
        if (tid < 384) {
            int r = tid / 12, q = tid % 12, cc = q >> 1, part = q & 1;
            float a2 = 0.f;
            #pragma unroll 8
            for (int k = 0; k < 64; k++)
                a2 += h2s[r * 132 + part * 64 + k] * w2s[(part * 64 + k) * 6 + cc];
            a2 += __shfl_xor(a2, 1);
            if (!part) outp[(size_t)(row0 + r) * 6 + cc] = fc2_b2[cc] + a2;
        }
    }
}

extern "C" void kernel_launch(void* const* d_in, const int* in_sizes, int n_in,
                              void* d_out, int out_size, void* d_ws, size_t ws_size,
                              hipStream_t stream) {
    const float* x       = (const float*)d_in[0];
    const float* fc1_W   = (const float*)d_in[1];
    const float* fc1_b   = (const float*)d_in[2];
    const float* ln_w    = (const float*)d_in[3];
    const float* ln_b    = (const float*)d_in[4];
    const float* in_W    = (const float*)d_in[5];
    const float* conv_w  = (const float*)d_in[6];
    const float* conv_b  = (const float*)d_in[7];
    const float* dt_bias = (const float*)d_in[8];
    const float* A_log   = (const float*)d_in[9];
    const float* Dp      = (const float*)d_in[10];
    const float* rms_w   = (const float*)d_in[11];
    const float* out_W   = (const float*)d_in[12];
    const float* fc2_W1  = (const float*)d_in[13];
    const float* fc2_b1  = (const float*)d_in[14];
    const float* fc2_W2  = (const float*)d_in[15];
    const float* fc2_b2  = (const float*)d_in[16];
    float* out = (float*)d_out;

    float* ws = (float*)d_ws;
    float* h     = ws;                            // NROWS*DM f32
    float* dtb   = h     + (size_t)NROWS * DM;    // NROWS*NH f32
    float* decay = dtb   + (size_t)NROWS * NH;    // 1024 f32
    short* sbase = (short*)(decay + 1024);
    short* hnb   = sbase;                          // NROWS*DM sh
    short* zb    = hnb   + (size_t)NROWS * DM;     // NROWS*DI sh
    short* xbc   = zb    + (size_t)NROWS * DI;     // NROWS*CDIM sh
    short* xcb   = xbc   + (size_t)NROWS * CDIM;   // NROWS*CDIM sh
    short* ybb   = xcb   + (size_t)NROWS * CDIM;   // NROWS*DI sh
    short* Slocb = ybb   + (size_t)NROWS * DI;     // 1024*4096 sh
    short* wb    = Slocb + (size_t)BATCH*NH*NCHUNK*HD*DST;

    prep_weights<<<1348, 256, 0, stream>>>(fc1_W, in_W, out_W, fc2_W1, wb);
    fc1_mfma<<<NROWS / 32, 512, 0, stream>>>(x, wb + WB_FC1, fc1_b, ln_w, ln_b, h, hnb);

    const float* lnw2 = ln_w + DM;
    const float* lnb2 = ln_b + DM;

    int coop = 0;
    hipDeviceGetAttribute(&coop, hipDeviceAttributeCooperativeLaunch, 0);

    for (int layer = 0; layer < 2; layer++) {
        bool done = false;
        if (coop) {
            int lay = layer;
            void* args[] = { (void*)&hnb, (void*)&wb, (void*)&zb, (void*)&xbc, (void*)&xcb,
                             (void*)&dtb, (void*)&dt_bias, (void*)&conv_w, (void*)&conv_b,
                             (void*)&A_log, (void*)&Dp, (void*)&Slocb, (void*)&decay,
                             (void*)&ybb, (void*)&rms_w, (void*)&lnw2, (void*)&lnb2, (void*)&h,
                             (void*)&fc2_b1, (void*)&fc2_W2, (void*)&fc2_b2, (void*)&out,
                             (void*)&lay };
            hipError_t err = hipLaunchCooperativeKernel((void*)layer_mega, dim3(512), dim3(512),
                                                        args, 0, stream);
            if (err == hipSuccess) done = true;
            else coop = 0;   // failed launch touched no data; use fallback from here on
        }
        if (!done) {
            inproj_mfma<<<dim3(NROWS / 64, 5), 512, 0, stream>>>(hnb, wb, zb, xbc, layer);
            conv_kernel<<<NROWS / 4, CDIM, 0, stream>>>(xbc, conv_w, conv_b, xcb,
                                                        hnb, wb, dt_bias, dtb, layer);
            chunk_state_mfma<<<BATCH*NH*NCHUNK, 256, 0, stream>>>(xcb, dtb, A_log, Slocb,
                                                                  decay, layer);
            chunk_out_mfma<<<BATCH*NH*NCHUNK, 256, 0, stream>>>(xcb, dtb, A_log, Dp, Slocb,
                                                                decay, ybb, layer);
            outproj_gate_mfma<<<NROWS / 32, 512, 0, stream>>>(ybb, zb, rms_w, wb,
                                                              lnw2, lnb2, h, hnb,
                                                              fc2_b1, fc2_W2, fc2_b2, out,
                                                              layer, layer == 1 ? 1 : 0);
        }
    }
}

// Round 11
// 244.725 us; speedup vs baseline: 5.8936x; 5.8936x over previous
//
#include <hip/hip_runtime.h>
#include <hip/hip_bf16.h>

// Dims
#define BATCH 16
#define SEQ 1024
#define NROWS (BATCH*SEQ)          // 16384 tokens
#define IN_DIM 768
#define DM 128
#define DIP 644
#define DI 256
#define CDIM 384
#define DST 64
#define NH 4
#define HD 64
#define CHUNK 64
#define NCHUNK (SEQ/CHUNK)         // 16

// bf16 weight area offsets (in shorts)
#define WB_FC1   0          // [128][768]
#define WB_IN    98304      // [2][644][128]
#define WB_OUT   263168     // [2][128][256]
#define WB_FC2   328704     // [128][128]
#define WB_TOTAL 345088

typedef __attribute__((ext_vector_type(8))) short short8;
typedef __attribute__((ext_vector_type(4))) float float4v;

// f32 -> bf16 (RNE) as raw short
__device__ __forceinline__ short f2b(float f) {
    unsigned u = __builtin_bit_cast(unsigned, f);
    u += 0x7fffu + ((u >> 16) & 1u);
    return (short)(u >> 16);
}
__device__ __forceinline__ float s2f(short s) {
    unsigned u = ((unsigned)(unsigned short)s) << 16;
    return __builtin_bit_cast(float, u);
}
__device__ __forceinline__ float silu(float a) { return a / (1.f + expf(-a)); }

// ---------------- weight prep: convert + transpose to bf16 ----------------
__global__ void prep_weights(const float* __restrict__ fc1_W, const float* __restrict__ in_W,
                             const float* __restrict__ out_W, const float* __restrict__ fc2_W1,
                             short* __restrict__ wb) {
    int idx = blockIdx.x * 256 + threadIdx.x;
    if (idx < 98304) {                       // fc1_Wt[n][k] <- fc1_W[k][n]
        int n = idx / 768, k = idx % 768;
        wb[WB_FC1 + idx] = f2b(fc1_W[k * 128 + n]);
        return;
    }
    idx -= 98304;
    if (idx < 2 * 82432) {                   // in_Wt[l][n][k] <- in_W[l][k][n]
        int l = idx / 82432, r = idx % 82432;
        int n = r / 128, k = r % 128;
        wb[WB_IN + idx] = f2b(in_W[(size_t)l * 82432 + k * 644 + n]);
        return;
    }
    idx -= 164864;
    if (idx < 2 * 32768) {                   // out_Wt[l][n][k] <- out_W[l][k][n]
        int l = idx / 32768, r = idx % 32768;
        int n = r / 256, k = r % 256;
        wb[WB_OUT + idx] = f2b(out_W[(size_t)l * 32768 + k * 128 + n]);
        return;
    }
    idx -= 65536;
    if (idx < 16384) {                       // fc2_W1t[n][k] <- fc2_W1[k][n]
        int n = idx / 128, k = idx % 128;
        wb[WB_FC2 + idx] = f2b(fc2_W1[k * 128 + n]);
    }
}

// ---------------- fc1 (MFMA, M=32, dbuf LDS, 1 barrier/K-tile) + PE + register-LN ----------------
__global__ __launch_bounds__(512) void fc1_mfma(const float* __restrict__ x,
                                                const short* __restrict__ wt,
                                                const float* __restrict__ bias,
                                                const float* __restrict__ lnw0,
                                                const float* __restrict__ lnb0,
                                                float* __restrict__ h,
                                                short* __restrict__ hnb) {
    __shared__ short As[2][32 * 72];
    __shared__ short Bt[2][128 * 72];
    __shared__ float ps1[32][4], ps2[32][4];
    int tid = threadIdx.x;
    int lane = tid & 63;
    int m = lane & 15;
    int quad = lane >> 4;
    int kq = quad * 8;
    int w = tid >> 6;              // 0..7
    int mrow = (w & 1) * 16;
    int ngrp = w >> 1;             // 0..3 -> cols ngrp*32 .. +31
    int ar = tid >> 4;             // 0..31
    int ac = (tid & 15) * 4;       // 0..60
    int row0 = blockIdx.x * 32;
    float4v acc[2];
    acc[0] = (float4v)0.f; acc[1] = (float4v)0.f;

#define FC1_STAGE(BI, KT) { \
        const float* src = x + (size_t)(row0 + ar) * IN_DIM + (KT) * 64 + ac; \
        float4 v = *(const float4*)src; \
        short4 pv; pv.x = f2b(v.x); pv.y = f2b(v.y); pv.z = f2b(v.z); pv.w = f2b(v.w); \
        *reinterpret_cast<short4*>(&As[BI][ar * 72 + ac]) = pv; \
        _Pragma("unroll") \
        for (int i = 0; i < 2; i++) { \
            int idx = tid + i * 512; \
            int n = idx >> 3, kk = (idx & 7) * 8; \
            *reinterpret_cast<short8*>(&Bt[BI][n * 72 + kk]) = \
                *reinterpret_cast<const short8*>(&wt[n * 768 + (KT) * 64 + kk]); \
        } }

    FC1_STAGE(0, 0)
    __syncthreads();
    int buf = 0;
    for (int kt = 0; kt < 12; kt++) {
        int nb = buf ^ 1;
        if (kt < 11) FC1_STAGE(nb, kt + 1)
        short8 a0 = *reinterpret_cast<const short8*>(&As[buf][(mrow + m) * 72 + kq]);
        short8 a1 = *reinterpret_cast<const short8*>(&As[buf][(mrow + m) * 72 + kq + 32]);
        #pragma unroll
        for (int nt = 0; nt < 2; nt++) {
            int bo = (ngrp * 32 + nt * 16 + m) * 72 + kq;
            short8 b0 = *reinterpret_cast<const short8*>(&Bt[buf][bo]);
            short8 b1 = *reinterpret_cast<const short8*>(&Bt[buf][bo + 32]);
            acc[nt] = __builtin_amdgcn_mfma_f32_16x16x32_bf16(a0, b0, acc[nt], 0, 0, 0);
            acc[nt] = __builtin_amdgcn_mfma_f32_16x16x32_bf16(a1, b1, acc[nt], 0, 0, 0);
        }
        __syncthreads();
        buf = nb;
    }
    float val[2][4];
    float s1r[4] = {0.f,0.f,0.f,0.f}, s2r[4] = {0.f,0.f,0.f,0.f};
    #pragma unroll
    for (int nt = 0; nt < 2; nt++) {
        int col = ngrp * 32 + nt * 16 + m;
        float bv = bias[col];
        float div = expf(-(float)(col & ~1) * 0.071955784f);
        #pragma unroll
        for (int r = 0; r < 4; r++) {
            int row = row0 + mrow + quad * 4 + r;
            int t = row & (SEQ - 1);
            float arg = (float)t * div;
            float pe = (col & 1) ? cosf(arg) : sinf(arg);
            float v = acc[nt][r] + bv + pe;
            val[nt][r] = v;
            s1r[r] += v; s2r[r] += v * v;
        }
    }
    #pragma unroll
    for (int o = 1; o < 16; o <<= 1) {
        #pragma unroll
        for (int r = 0; r < 4; r++) {
            s1r[r] += __shfl_xor(s1r[r], o);
            s2r[r] += __shfl_xor(s2r[r], o);
        }
    }
    if (m == 0) {
        #pragma unroll
        for (int r = 0; r < 4; r++) {
            ps1[mrow + quad * 4 + r][ngrp] = s1r[r];
            ps2[mrow + quad * 4 + r][ngrp] = s2r[r];
        }
    }
    __syncthreads();
    #pragma unroll
    for (int r = 0; r < 4; r++) {
        int rl = mrow + quad * 4 + r;
        float s1 = ps1[rl][0] + ps1[rl][1] + ps1[rl][2] + ps1[rl][3];
        float s2 = ps2[rl][0] + ps2[rl][1] + ps2[rl][2] + ps2[rl][3];
        float mu = s1 * (1.f / 128.f);
        float rs = rsqrtf(s2 * (1.f / 128.f) - mu * mu + 1e-5f);
        int row = row0 + rl;
        #pragma unroll
        for (int nt = 0; nt < 2; nt++) {
            int col = ngrp * 32 + nt * 16 + m;
            float v = val[nt][r];
            h[(size_t)row * DM + col] = v;
            hnb[(size_t)row * DM + col] = f2b((v - mu) * rs * lnw0[col] + lnb0[col]);
        }
    }
}

// ---------------- in_proj: full-K single-barrier (A 64x128 + B 128x128 staged once) ----------------
__global__ __launch_bounds__(512) void inproj_mfma(const short* __restrict__ hnb,
                                                   const short* __restrict__ wb,
                                                   short* __restrict__ zb,
                                                   short* __restrict__ xbc,
                                                   int layer) {
    __shared__ short As[64 * 136];     // full A, K=128 (+8 pad)
    __shared__ short Bt[128 * 136];    // full B tile, K=128 (+8 pad)
    int tid = threadIdx.x;
    int lane = tid & 63;
    int m = lane & 15;
    int kq = (lane >> 4) * 8;
    int w = tid >> 6;
    int mrow = (w & 3) * 16;
    int ngrp = w >> 2;
    int row0 = blockIdx.x * 64;
    int ncol0 = blockIdx.y * 128;      // 0,128,256,384,512 — all cols < 640 valid
    const short* wt = wb + WB_IN + (size_t)layer * 82432;
    {   // stage A: contiguous 16KB slab of hnb
        const short* src = hnb + (size_t)row0 * DM;
        #pragma unroll
        for (int i = 0; i < 2; i++) {
            int u = i * 512 + tid;         // 0..1023 short8 units
            *reinterpret_cast<short8*>(&As[(u >> 4) * 136 + (u & 15) * 8]) =
                *reinterpret_cast<const short8*>(&src[u * 8]);
        }
        #pragma unroll
        for (int i = 0; i < 4; i++) {      // stage B: 128 rows x 128 k
            int u = i * 512 + tid;         // 0..2047 short8 units
            int n = u >> 4, c8 = (u & 15) * 8;
            *reinterpret_cast<short8*>(&Bt[n * 136 + c8]) =
                *reinterpret_cast<const short8*>(&wt[(ncol0 + n) * 128 + c8]);
        }
    }
    __syncthreads();
    float4v acc[4];
    acc[0] = (float4v)0.f; acc[1] = (float4v)0.f; acc[2] = (float4v)0.f; acc[3] = (float4v)0.f;
    #pragma unroll
    for (int ks = 0; ks < 4; ks++) {       // K = 4 x 32
        short8 a = *reinterpret_cast<const short8*>(&As[(mrow + m) * 136 + ks * 32 + kq]);
        #pragma unroll
        for (int nt = 0; nt < 4; nt++) {
            short8 b = *reinterpret_cast<const short8*>(
                &Bt[(ngrp * 64 + nt * 16 + m) * 136 + ks * 32 + kq]);
            acc[nt] = __builtin_amdgcn_mfma_f32_16x16x32_bf16(a, b, acc[nt], 0, 0, 0);
        }
    }
    int colbase = ncol0 + ngrp * 64;
    if (ncol0 < DI) {                   // tiles 0,1 -> z
        #pragma unroll
        for (int nt = 0; nt < 4; nt++) {
            int col = colbase + nt * 16 + m;
            #pragma unroll
            for (int r = 0; r < 4; r++) {
                int row = row0 + mrow + (lane >> 4) * 4 + r;
                zb[(size_t)row * DI + col] = f2b(acc[nt][r]);
            }
        }
    } else {                            // tiles 2,3,4 -> xBC
        int xbase = colbase - DI;
        #pragma unroll
        for (int nt = 0; nt < 4; nt++) {
            int col = xbase + nt * 16 + m;
            #pragma unroll
            for (int r = 0; r < 4; r++) {
                int row = row0 + mrow + (lane >> 4) * 4 + r;
                xbc[(size_t)row * CDIM + col] = f2b(acc[nt][r]);
            }
        }
    }
}

// ---------------- causal conv(4) + SiLU, 4 tokens/block + fused dt GEMV/softplus ----------------
__global__ void conv_kernel(const short* __restrict__ xbc,
                            const float* __restrict__ convw, const float* __restrict__ convb,
                            short* __restrict__ xcb,
                            const short* __restrict__ hnb, const short* __restrict__ wb,
                            const float* __restrict__ dt_bias, float* __restrict__ dtb,
                            int layer) {
    int c = threadIdx.x;            // 384
    int row0 = blockIdx.x * 4;
    int l0 = row0 & (SEQ - 1);
    const float* cw = convw + (size_t)layer * 4 * CDIM;
    float w0 = cw[c], w1 = cw[CDIM + c], w2 = cw[2 * CDIM + c], w3 = cw[3 * CDIM + c];
    float bb = convb[layer * CDIM + c];
    float v[7];
    #pragma unroll
    for (int i = 0; i < 7; i++) {
        int rr = row0 + i - 3;
        v[i] = (l0 + i - 3 >= 0) ? s2f(xbc[(size_t)rr * CDIM + c]) : 0.f;
    }
    #pragma unroll
    for (int j = 0; j < 4; j++) {
        float acc = bb + w0 * v[j] + w1 * v[j + 1] + w2 * v[j + 2] + w3 * v[j + 3];
        xcb[(size_t)(row0 + j) * CDIM + c] = f2b(silu(acc));
    }
    // dt GEMV: dt[row][hh] = softplus(hnb[row] . in_Wt[640+hh] + dt_bias[hh])
    if (c < 128) {
        int r = c >> 5;             // 0..3 row
        int rem = c & 31;
        int hh = rem >> 3;          // 0..3 head
        int part = rem & 7;         // 0..7 -> K slice of 16
        const short* hrow = hnb + (size_t)(row0 + r) * DM + part * 16;
        const short* wrow = wb + WB_IN + (size_t)layer * 82432 + (640 + hh) * 128 + part * 16;
        short8 hv0 = *reinterpret_cast<const short8*>(hrow);
        short8 hv1 = *reinterpret_cast<const short8*>(hrow + 8);
        short8 wv0 = *reinterpret_cast<const short8*>(wrow);
        short8 wv1 = *reinterpret_cast<const short8*>(wrow + 8);
        float s = 0.f;
        #pragma unroll
        for (int q = 0; q < 8; q++)
            s += s2f(hv0[q]) * s2f(wv0[q]) + s2f(hv1[q]) * s2f(wv1[q]);
        s += __shfl_xor(s, 1);
        s += __shfl_xor(s, 2);
        s += __shfl_xor(s, 4);
        if (part == 0) {
            float raw = s + dt_bias[layer * NH + hh];
            float dt = (raw > 20.f) ? raw : log1pf(expf(raw));
            dtb[(size_t)(row0 + r) * NH + hh] = dt;
        }
    }
}

// ---------------- chunk A (MFMA): S[p][n] -> bf16 ----------------
__global__ __launch_bounds__(256) void chunk_state_mfma(const short* __restrict__ xcb,
                                                        const float* __restrict__ dtb,
                                                        const float* __restrict__ A_log,
                                                        short* __restrict__ Slocb,
                                                        float* __restrict__ decay, int layer) {
    __shared__ short XTw[64 * 72];   // [p][t]
    __shared__ short BT[64 * 72];    // [n][t]
    __shared__ float wst[64];
    int bid = blockIdx.x;
    int c  = bid & (NCHUNK - 1);
    int hh = (bid >> 4) & (NH - 1);
    int b  = bid >> 6;
    int tid = threadIdx.x;
    int row0 = b * SEQ + c * CHUNK;
    float A = -expf(A_log[layer * NH + hh]);

    if (tid < CHUNK) {
        float dtv = dtb[(size_t)(row0 + tid) * NH + hh];
        float l = dtv * A;
        #pragma unroll
        for (int o = 1; o < 64; o <<= 1) { float v = __shfl_up(l, o); if (tid >= o) l += v; }
        float Ltot = __shfl(l, 63);
        wst[tid] = expf(Ltot - l) * dtv;
        if (tid == 63) decay[bid] = expf(Ltot);
    }
    __syncthreads();
    {
        int p = tid & 63;
        int tb0 = tid >> 6;
        #pragma unroll
        for (int i = 0; i < 2; i++) {
            int t0 = (tb0 + i * 4) * 8;
            short8 xv, bv;
            #pragma unroll
            for (int j = 0; j < 8; j++) {
                int t = t0 + j;
                const short* xr = xcb + (size_t)(row0 + t) * CDIM;
                xv[j] = f2b(s2f(xr[hh * HD + p]) * wst[t]);
                bv[j] = xr[DI + p];
            }
            *reinterpret_cast<short8*>(&XTw[p * 72 + t0]) = xv;
            *reinterpret_cast<short8*>(&BT[p * 72 + t0]) = bv;
        }
    }
    __syncthreads();

    int lane = tid & 63;
    int m = lane & 15;
    int kq = (lane >> 4) * 8;
    int w = tid >> 6;
    int a_off = (w * 16 + m) * 72 + kq;
    float4v acc[4];
    acc[0] = (float4v)0.f; acc[1] = (float4v)0.f; acc[2] = (float4v)0.f; acc[3] = (float4v)0.f;
    short8 a0 = *reinterpret_cast<const short8*>(&XTw[a_off]);
    short8 a1 = *reinterpret_cast<const short8*>(&XTw[a_off + 32]);
    #pragma unroll
    for (int nt = 0; nt < 4; nt++) {
        int bo = (nt * 16 + m) * 72 + kq;
        short8 b0 = *reinterpret_cast<const short8*>(&BT[bo]);
        short8 b1 = *reinterpret_cast<const short8*>(&BT[bo + 32]);
        acc[nt] = __builtin_amdgcn_mfma_f32_16x16x32_bf16(a0, b0, acc[nt], 0, 0, 0);
        acc[nt] = __builtin_amdgcn_mfma_f32_16x16x32_bf16(a1, b1, acc[nt], 0, 0, 0);
    }
    short* Sp = Slocb + (size_t)bid * (HD * DST);
    int tq = (lane >> 4) * 4;
    #pragma unroll
    for (int nt = 0; nt < 4; nt++) {
        #pragma unroll
        for (int r = 0; r < 4; r++) {
            int p = w * 16 + tq + r;
            int n = nt * 16 + m;
            Sp[p * DST + n] = f2b(acc[nt][r]);   // [p][n] bf16
        }
    }
}

// ---------------- chunk C (MFMA) + fused inter-chunk recurrence: outputs -> y bf16 ----------------
__global__ __launch_bounds__(256) void chunk_out_mfma(const short* __restrict__ xcb,
                                                      const float* __restrict__ dtb,
                                                      const float* __restrict__ A_log,
                                                      const float* __restrict__ Dpw,
                                                      const short* __restrict__ Slocb,
                                                      const float* __restrict__ decay,
                                                      short* __restrict__ ybb, int layer) {
    __shared__ short Cb[64 * 72];    // [t][n]
    __shared__ short Bb[64 * 72];    // [s][n], later M[t][s]
    __shared__ short XT[64 * 72];    // [p][t]
    __shared__ short HT[64 * 72];    // [p][n]
    __shared__ float Ls[64], dts[64];
    int bid = blockIdx.x;
    int c  = bid & (NCHUNK - 1);
    int hh = (bid >> 4) & (NH - 1);
    int b  = bid >> 6;
    int tid = threadIdx.x;
    int row0 = b * SEQ + c * CHUNK;
    int bh0 = bid & ~(NCHUNK - 1);
    float A = -expf(A_log[layer * NH + hh]);
    float Dph = Dpw[layer * NH + hh];

    if (tid < CHUNK) {
        float dtv = dtb[(size_t)(row0 + tid) * NH + hh];
        float l = dtv * A;
        #pragma unroll
        for (int o = 1; o < 64; o <<= 1) { float v = __shfl_up(l, o); if (tid >= o) l += v; }
        Ls[tid] = l;
        dts[tid] = dtv;
    }
    {   // fused inter-chunk recurrence: hstart in registers
        float hreg[16];
        #pragma unroll
        for (int k = 0; k < 16; k++) hreg[k] = 0.f;
        for (int j = 0; j < c; j++) {
            float d = decay[bh0 + j];
            const short* Sp = Slocb + (size_t)(bh0 + j) * (HD * DST) + tid * 16;
            short8 s0 = *reinterpret_cast<const short8*>(Sp);
            short8 s1 = *reinterpret_cast<const short8*>(Sp + 8);
            #pragma unroll
            for (int k = 0; k < 8; k++) {
                hreg[k]     = d * hreg[k]     + s2f(s0[k]);
                hreg[8 + k] = d * hreg[8 + k] + s2f(s1[k]);
            }
        }
        int p = tid >> 2;
        int n0 = (tid & 3) * 16;
        short8 h0, h1;
        #pragma unroll
        for (int k = 0; k < 8; k++) { h0[k] = f2b(hreg[k]); h1[k] = f2b(hreg[8 + k]); }
        *reinterpret_cast<short8*>(&HT[p * 72 + n0]) = h0;
        *reinterpret_cast<short8*>(&HT[p * 72 + n0 + 8]) = h1;
    }
    {
        int p = tid & 63;
        int tb0 = tid >> 6;
        #pragma unroll
        for (int i = 0; i < 2; i++) {
            int t0 = (tb0 + i * 4) * 8;
            short8 xv;
            #pragma unroll
            for (int j = 0; j < 8; j++)
                xv[j] = xcb[(size_t)(row0 + t0 + j) * CDIM + hh * HD + p];
            *reinterpret_cast<short8*>(&XT[p * 72 + t0]) = xv;
        }
    }
    #pragma unroll
    for (int i = 0; i < 2; i++) {
        int idx = tid + i * 256;
        int t = idx >> 3, cb = (idx & 7) * 8;
        const short* xr = xcb + (size_t)(row0 + t) * CDIM;
        *reinterpret_cast<short8*>(&Bb[t * 72 + cb]) =
            *reinterpret_cast<const short8*>(&xr[DI + cb]);
        *reinterpret_cast<short8*>(&Cb[t * 72 + cb]) =
            *reinterpret_cast<const short8*>(&xr[DI + DST + cb]);
    }
    __syncthreads();

    int lane = tid & 63;
    int m = lane & 15;
    int kq = (lane >> 4) * 8;
    int w = tid >> 6;
    int tq = (lane >> 4) * 4;
    int a_off = (w * 16 + m) * 72 + kq;

    short8 ca0 = *reinterpret_cast<const short8*>(&Cb[a_off]);
    short8 ca1 = *reinterpret_cast<const short8*>(&Cb[a_off + 32]);

    float4v g[4], ir[4];
    #pragma unroll
    for (int i = 0; i < 4; i++) { g[i] = (float4v)0.f; ir[i] = (float4v)0.f; }
    #pragma unroll
    for (int st = 0; st < 4; st++) {
        int bo = (st * 16 + m) * 72 + kq;
        short8 b0 = *reinterpret_cast<const short8*>(&Bb[bo]);
        short8 b1 = *reinterpret_cast<const short8*>(&Bb[bo + 32]);
        g[st] = __builtin_amdgcn_mfma_f32_16x16x32_bf16(ca0, b0, g[st], 0, 0, 0);
        g[st] = __builtin_amdgcn_mfma_f32_16x16x32_bf16(ca1, b1, g[st], 0, 0, 0);
        short8 h0 = *reinterpret_cast<const short8*>(&HT[bo]);
        short8 h1 = *reinterpret_cast<const short8*>(&HT[bo + 32]);
        ir[st] = __builtin_amdgcn_mfma_f32_16x16x32_bf16(ca0, h0, ir[st], 0, 0, 0);
        ir[st] = __builtin_amdgcn_mfma_f32_16x16x32_bf16(ca1, h1, ir[st], 0, 0, 0);
    }
    __syncthreads();
    #pragma unroll
    for (int st = 0; st < 4; st++) {
        #pragma unroll
        for (int r = 0; r < 4; r++) {
            int t = w * 16 + tq + r;
            int s = st * 16 + m;
            float mv = 0.f;
            if (s <= t) mv = g[st][r] * expf(Ls[t] - Ls[s]) * dts[s];
            Bb[t * 72 + s] = f2b(mv);
        }
    }
    __syncthreads();
    float4v yi[4];
    #pragma unroll
    for (int i = 0; i < 4; i++) yi[i] = (float4v)0.f;
    short8 ma0 = *reinterpret_cast<const short8*>(&Bb[a_off]);
    short8 ma1 = *reinterpret_cast<const short8*>(&Bb[a_off + 32]);
    #pragma unroll
    for (int pt = 0; pt < 4; pt++) {
        int bo = (pt * 16 + m) * 72 + kq;
        short8 x0 = *reinterpret_cast<const short8*>(&XT[bo]);
        short8 x1 = *reinterpret_cast<const short8*>(&XT[bo + 32]);
        yi[pt] = __builtin_amdgcn_mfma_f32_16x16x32_bf16(ma0, x0, yi[pt], 0, 0, 0);
        yi[pt] = __builtin_amdgcn_mfma_f32_16x16x32_bf16(ma1, x1, yi[pt], 0, 0, 0);
    }
    #pragma unroll
    for (int r = 0; r < 4; r++) {
        int t = w * 16 + tq + r;
        float et = expf(Ls[t]);
        short* yr = ybb + (size_t)(row0 + t) * DI + hh * HD;
        #pragma unroll
        for (int pt = 0; pt < 4; pt++) {
            int p = pt * 16 + m;
            float xv = s2f(XT[p * 72 + t]);
            yr[p] = f2b(yi[pt][r] + et * ir[pt][r] + Dph * xv);
        }
    }
}

// ---------------- out_proj + gate/RMSNorm + residual (+ LN for layer0, + fc2 for layer1) ----------------
// M=32 rows/block, grid 512 (2 blocks/CU), single y/z read, dbuf B (1 barrier/K-tile)
__global__ __launch_bounds__(512) void outproj_gate_mfma(const short* __restrict__ ybb,
                                                         const short* __restrict__ zb,
                                                         const float* __restrict__ rmsw,
                                                         const short* __restrict__ wb,
                                                         const float* __restrict__ lnw2,
                                                         const float* __restrict__ lnb2,
                                                         float* __restrict__ h,
                                                         short* __restrict__ hnb,
                                                         const float* __restrict__ fc2_b1,
                                                         const float* __restrict__ fc2_W2,
                                                         const float* __restrict__ fc2_b2,
                                                         float* __restrict__ outp,
                                                         int layer, int do_fc2) {
    __shared__ __align__(16) short As[32 * 264];      // A [32][256+8]; overlays: hs/As2/h2s
    __shared__ __align__(16) short Bt[2][128 * 72];   // dbuf B k-tiles; overlay: Bt2 [128][136]
    __shared__ float w2s[768];
    int tid = threadIdx.x;
    int lane = tid & 63;
    int m = lane & 15;
    int quad = lane >> 4;
    int kq = quad * 8;
    int w = tid >> 6;              // 0..7
    int mrow = (w & 1) * 16;
    int ngrp = w >> 1;             // 0..3 -> 32 cols each
    int row0 = blockIdx.x * 32;
    const short* wt = wb + WB_OUT + (size_t)layer * 32768;
    if (do_fc2)
        for (int i = tid; i < 768; i += 512) w2s[i] = fc2_W2[i];
    // phase 1: v = y*silu(z); RMS over 256; A = bf16(v*rs*rmsw)  (single global read)
    {
        int r = tid >> 4, j = tid & 15;
        const short* yr = ybb + (size_t)(row0 + r) * DI + j * 16;
        const short* zr = zb + (size_t)(row0 + r) * DI + j * 16;
        short8 y0 = *reinterpret_cast<const short8*>(yr);
        short8 y1 = *reinterpret_cast<const short8*>(yr + 8);
        short8 z0 = *reinterpret_cast<const short8*>(zr);
        short8 z1 = *reinterpret_cast<const short8*>(zr + 8);
        float v[16]; float s2 = 0.f;
        #pragma unroll
        for (int q = 0; q < 8; q++) {
            v[q]     = s2f(y0[q]) * silu(s2f(z0[q]));
            v[8 + q] = s2f(y1[q]) * silu(s2f(z1[q]));
        }
        #pragma unroll
        for (int q = 0; q < 16; q++) s2 += v[q] * v[q];
        #pragma unroll
        for (int o = 1; o < 16; o <<= 1) s2 += __shfl_xor(s2, o);
        float rs = rsqrtf(s2 * (1.f / 256.f) + 1e-5f);
        const float* rw = rmsw + layer * DI + j * 16;
        short8 a0, a1;
        #pragma unroll
        for (int q = 0; q < 8; q++) {
            a0[q] = f2b(v[q] * rs * rw[q]);
            a1[q] = f2b(v[8 + q] * rs * rw[8 + q]);
        }
        *reinterpret_cast<short8*>(&As[r * 264 + j * 16]) = a0;
        *reinterpret_cast<short8*>(&As[r * 264 + j * 16 + 8]) = a1;
    }
    {   // stage B k-tile 0
        int n = tid >> 2, kk = (tid & 3) * 16;
        *reinterpret_cast<short8*>(&Bt[0][n * 72 + kk]) =
            *reinterpret_cast<const short8*>(&wt[n * 256 + kk]);
        *reinterpret_cast<short8*>(&Bt[0][n * 72 + kk + 8]) =
            *reinterpret_cast<const short8*>(&wt[n * 256 + kk + 8]);
    }
    __syncthreads();
    float4v acc[2];
    acc[0] = (float4v)0.f; acc[1] = (float4v)0.f;
    int buf = 0;
    for (int kt = 0; kt < 4; kt++) {
        if (kt < 3) {
            int n = tid >> 2, kk = (tid & 3) * 16;
            *reinterpret_cast<short8*>(&Bt[buf ^ 1][n * 72 + kk]) =
                *reinterpret_cast<const short8*>(&wt[n * 256 + (kt + 1) * 64 + kk]);
            *reinterpret_cast<short8*>(&Bt[buf ^ 1][n * 72 + kk + 8]) =
                *reinterpret_cast<const short8*>(&wt[n * 256 + (kt + 1) * 64 + kk + 8]);
        }
        short8 a0 = *reinterpret_cast<const short8*>(&As[(mrow + m) * 264 + kt * 64 + kq]);
        short8 a1 = *reinterpret_cast<const short8*>(&As[(mrow + m) * 264 + kt * 64 + kq + 32]);
        #pragma unroll
        for (int nt = 0; nt < 2; nt++) {
            int bo = (ngrp * 32 + nt * 16 + m) * 72 + kq;
            short8 b0 = *reinterpret_cast<const short8*>(&Bt[buf][bo]);
            short8 b1 = *reinterpret_cast<const short8*>(&Bt[buf][bo + 32]);
            acc[nt] = __builtin_amdgcn_mfma_f32_16x16x32_bf16(a0, b0, acc[nt], 0, 0, 0);
            acc[nt] = __builtin_amdgcn_mfma_f32_16x16x32_bf16(a1, b1, acc[nt], 0, 0, 0);
        }
        __syncthreads();
        buf ^= 1;
    }
    // epilogue: acc -> hs overlay (As reads complete after final sync)
    float* hs = (float*)As;        // [32][132]
    #pragma unroll
    for (int nt = 0; nt < 2; nt++) {
        int col = ngrp * 32 + nt * 16 + m;
        #pragma unroll
        for (int r = 0; r < 4; r++)
            hs[(mrow + quad * 4 + r) * 132 + col] = acc[nt][r];
    }
    __syncthreads();
    // residual add: 16 threads/row, 8 cols each
    int er = tid >> 4, ej = tid & 15;
    int erow = row0 + er;
    float vals[8];
    float s1 = 0.f, s2v = 0.f;
    {
        const float* hsrc = h + (size_t)erow * DM + ej * 8;
        float4 h0 = *(const float4*)hsrc;
        float4 h1 = *(const float4*)(hsrc + 4);
        const float* hrow = &hs[er * 132 + ej * 8];
        float4 q0 = *(const float4*)hrow;
        float4 q1 = *(const float4*)(hrow + 4);
        vals[0] = h0.x + q0.x; vals[1] = h0.y + q0.y; vals[2] = h0.z + q0.z; vals[3] = h0.w + q0.w;
        vals[4] = h1.x + q1.x; vals[5] = h1.y + q1.y; vals[6] = h1.z + q1.z; vals[7] = h1.w + q1.w;
        #pragma unroll
        for (int i = 0; i < 8; i++) { s1 += vals[i]; s2v += vals[i] * vals[i]; }
    }
    if (!do_fc2) {
        #pragma unroll
        for (int o = 1; o < 16; o <<= 1) { s1 += __shfl_xor(s1, o); s2v += __shfl_xor(s2v, o); }
        float* hdst = h + (size_t)erow * DM + ej * 8;
        *(float4*)hdst = make_float4(vals[0], vals[1], vals[2], vals[3]);
        *(float4*)(hdst + 4) = make_float4(vals[4], vals[5], vals[6], vals[7]);
        float mu = s1 * (1.f / 128.f);
        float rs2 = rsqrtf(s2v * (1.f / 128.f) - mu * mu + 1e-5f);
        const float* lw = lnw2 + ej * 8;
        const float* lb = lnb2 + ej * 8;
        short8 a0;
        #pragma unroll
        for (int i = 0; i < 8; i++) a0[i] = f2b((vals[i] - mu) * rs2 * lw[i] + lb[i]);
        *reinterpret_cast<short8*>(hnb + (size_t)erow * DM + ej * 8) = a0;
        return;
    }
    // ---- fused fc2a + fc2b (layer 1): vals -> As2, full Bt2 stage, 8 MFMA, leaky, 128->6 ----
    __syncthreads();               // all hs reads done; safe to overwrite
    short* As2 = (short*)As;       // [32][136]
    {
        short8 ap;
        #pragma unroll
        for (int i = 0; i < 8; i++) ap[i] = f2b(vals[i]);
        *reinterpret_cast<short8*>(&As2[er * 136 + ej * 8]) = ap;
    }
    const short* wtf = wb + WB_FC2;
    short* Bt2 = (short*)Bt;       // [128][136]
    {
        int n = tid >> 2, kk = (tid & 3) * 32;
        #pragma unroll
        for (int i = 0; i < 4; i++)
            *reinterpret_cast<short8*>(&Bt2[n * 136 + kk + i * 8]) =
                *reinterpret_cast<const short8*>(&wtf[n * 128 + kk + i * 8]);
    }
    __syncthreads();
    float4v acc2[2];
    acc2[0] = (float4v)0.f; acc2[1] = (float4v)0.f;
    #pragma unroll
    for (int kt = 0; kt < 2; kt++) {
        int k0 = kt * 64;
        short8 a0 = *reinterpret_cast<const short8*>(&As2[(mrow + m) * 136 + k0 + kq]);
        short8 a1 = *reinterpret_cast<const short8*>(&As2[(mrow + m) * 136 + k0 + kq + 32]);
        #pragma unroll
        for (int nt = 0; nt < 2; nt++) {
            int bo = (ngrp * 32 + nt * 16 + m) * 136 + k0 + kq;
            short8 b0 = *reinterpret_cast<const short8*>(&Bt2[bo]);
            short8 b1 = *reinterpret_cast<const short8*>(&Bt2[bo + 32]);
            acc2[nt] = __builtin_amdgcn_mfma_f32_16x16x32_bf16(a0, b0, acc2[nt], 0, 0, 0);
            acc2[nt] = __builtin_amdgcn_mfma_f32_16x16x32_bf16(a1, b1, acc2[nt], 0, 0, 0);
        }
    }
    __syncthreads();               // As2/Bt2 reads done
    float* h2s = (float*)As;       // [32][132]
    #pragma unroll
    for (int nt = 0; nt < 2; nt++) {
        int col = ngrp * 32 + nt * 16 + m;
        float bv = fc2_b1[col];
        #pragma unroll
        for (int r = 0; r < 4; r++) {
            float o = acc2[nt][r] + bv;
            h2s[(mrow + quad * 4 + r) * 132 + col] = (o > 0.f) ? o : 0.1f * o;
        }
    }
    __syncthreads();
    if (tid < 384) {
        int r = tid / 12, q = tid % 12, cc = q >> 1, part = q & 1;
        float a2 = 0.f;
        #pragma unroll 8
        for (int k = 0; k < 64; k++)
            a2 += h2s[r * 132 + part * 64 + k] * w2s[(part * 64 + k) * 6 + cc];
        a2 += __shfl_xor(a2, 1);
        if (!part) outp[(size_t)(row0 + r) * 6 + cc] = fc2_b2[cc] + a2;
    }
}

extern "C" void kernel_launch(void* const* d_in, const int* in_sizes, int n_in,
                              void* d_out, int out_size, void* d_ws, size_t ws_size,
                              hipStream_t stream) {
    const float* x       = (const float*)d_in[0];
    const float* fc1_W   = (const float*)d_in[1];
    const float* fc1_b   = (const float*)d_in[2];
    const float* ln_w    = (const float*)d_in[3];
    const float* ln_b    = (const float*)d_in[4];
    const float* in_W    = (const float*)d_in[5];
    const float* conv_w  = (const float*)d_in[6];
    const float* conv_b  = (const float*)d_in[7];
    const float* dt_bias = (const float*)d_in[8];
    const float* A_log   = (const float*)d_in[9];
    const float* Dp      = (const float*)d_in[10];
    const float* rms_w   = (const float*)d_in[11];
    const float* out_W   = (const float*)d_in[12];
    const float* fc2_W1  = (const float*)d_in[13];
    const float* fc2_b1  = (const float*)d_in[14];
    const float* fc2_W2  = (const float*)d_in[15];
    const float* fc2_b2  = (const float*)d_in[16];
    float* out = (float*)d_out;

    float* ws = (float*)d_ws;
    float* h     = ws;                            // NROWS*DM f32
    float* dtb   = h     + (size_t)NROWS * DM;    // NROWS*NH f32
    float* decay = dtb   + (size_t)NROWS * NH;    // 1024 f32
    short* sbase = (short*)(decay + 1024);
    short* hnb   = sbase;                          // NROWS*DM sh
    short* zb    = hnb   + (size_t)NROWS * DM;     // NROWS*DI sh
    short* xbc   = zb    + (size_t)NROWS * DI;     // NROWS*CDIM sh
    short* xcb   = xbc   + (size_t)NROWS * CDIM;   // NROWS*CDIM sh
    short* ybb   = xcb   + (size_t)NROWS * CDIM;   // NROWS*DI sh
    short* Slocb = ybb   + (size_t)NROWS * DI;     // 1024*4096 sh
    short* wb    = Slocb + (size_t)BATCH*NH*NCHUNK*HD*DST;

    prep_weights<<<1348, 256, 0, stream>>>(fc1_W, in_W, out_W, fc2_W1, wb);
    fc1_mfma<<<NROWS / 32, 512, 0, stream>>>(x, wb + WB_FC1, fc1_b, ln_w, ln_b, h, hnb);

    for (int layer = 0; layer < 2; layer++) {
        inproj_mfma<<<dim3(NROWS / 64, 5), 512, 0, stream>>>(hnb, wb, zb, xbc, layer);
        conv_kernel<<<NROWS / 4, CDIM, 0, stream>>>(xbc, conv_w, conv_b, xcb,
                                                    hnb, wb, dt_bias, dtb, layer);
        chunk_state_mfma<<<BATCH*NH*NCHUNK, 256, 0, stream>>>(xcb, dtb, A_log, Slocb, decay, layer);
        chunk_out_mfma<<<BATCH*NH*NCHUNK, 256, 0, stream>>>(xcb, dtb, A_log, Dp, Slocb, decay,
                                                            ybb, layer);
        outproj_gate_mfma<<<NROWS / 32, 512, 0, stream>>>(ybb, zb, rms_w, wb,
                                                          ln_w + DM, ln_b + DM, h, hnb,
                                                          fc2_b1, fc2_W2, fc2_b2, out,
                                                          layer, layer == 1 ? 1 : 0);
    }
}